// Round 8
// baseline (224.744 us; speedup 1.0000x reference)
//
#include <hip/hip_runtime.h>
#include <hip/hip_bf16.h>

typedef unsigned int u32;
typedef unsigned short u16;
typedef short s8v __attribute__((ext_vector_type(8)));
typedef short s4v __attribute__((ext_vector_type(4)));
typedef float f4v __attribute__((ext_vector_type(4)));
typedef u32 u32x2 __attribute__((ext_vector_type(2)));

// Problem constants: B=2, L=4096, D=1024, HEADS=16, KEY=SPH=64, STEP=3
// new_len=4098, blocks P=1366, combos = B*3*H = 96
#define NBLK 1366
#define VROW 1376   // padded V row stride (16B aligned)
#define QSCALE 0.18033688011112042f   // 0.125 * log2(e), folded into Q

__device__ __forceinline__ u16 f2b(float f) {
  u32 u = __builtin_bit_cast(u32, f);
  u = (u + 0x7FFFu + ((u >> 16) & 1u)) >> 16;
  return (u16)u;
}

__device__ __forceinline__ u32 cvtpk(float a, float b) {
  u32 r;
  asm("v_cvt_pk_bf16_f32 %0, %1, %2" : "=v"(r) : "v"(a), "v"(b));
  return r;
}

__device__ __forceinline__ float fexp2(float x) {
#if defined(__has_builtin)
#if __has_builtin(__builtin_amdgcn_exp2f)
  return __builtin_amdgcn_exp2f(x);
#define FEXP2_DONE 1
#endif
#endif
#ifndef FEXP2_DONE
  float r;
  asm("v_exp_f32 %0, %1" : "=v"(r) : "v"(x));
  return r;
#endif
}

__device__ __forceinline__ void gll16(const void* g, void* l) {
  __builtin_amdgcn_global_load_lds(
      (const __attribute__((address_space(1))) u32*)g,
      (__attribute__((address_space(3))) u32*)l, 16, 0, 0);
}

__device__ __forceinline__ f4v mfma32(s8v a, s8v b, f4v c) {
  return __builtin_amdgcn_mfma_f32_16x16x32_bf16(a, b, c, 0, 0, 0);
}

__device__ __forceinline__ f4v mfma16(s4v a, s4v b, f4v c) {
#if defined(__has_builtin)
#if __has_builtin(__builtin_amdgcn_mfma_f32_16x16x16bf16_1k)
#define MFMA16_BUILTIN 1
#endif
#endif
#ifdef MFMA16_BUILTIN
  return __builtin_amdgcn_mfma_f32_16x16x16bf16_1k(a, b, c, 0, 0, 0);
#else
  f4v d;
  asm("v_mfma_f32_16x16x16_bf16 %0, %1, %2, %3" : "=v"(d) : "v"(a), "v"(b), "v"(c));
  return d;
#endif
}

// ---- pass 1: x (f32, [2][4096][1024]) -> xb (bf16, [8320][1024]); rows for
// padded t (4096,4097) and m>=8196 are zero.
__global__ __launch_bounds__(256) void k_convert_x(const float* __restrict__ x,
                                                   u16* __restrict__ xb) {
  int gid = blockIdx.x * 256 + threadIdx.x;
  long base = (long)gid * 8;
  if (base >= 8320L * 1024L) return;
  int m = (int)(base >> 10);
  int c = (int)(base & 1023);
  int b = m / 4098;
  int t = m - b * 4098;
  s8v pack;
  if (m < 8196 && t < 4096) {
    const float* src = x + ((size_t)b * 4096 + t) * 1024 + c;
    float4 v0 = *(const float4*)(src);
    float4 v1 = *(const float4*)(src + 4);
    pack[0] = (short)f2b(v0.x); pack[1] = (short)f2b(v0.y);
    pack[2] = (short)f2b(v0.z); pack[3] = (short)f2b(v0.w);
    pack[4] = (short)f2b(v1.x); pack[5] = (short)f2b(v1.y);
    pack[6] = (short)f2b(v1.z); pack[7] = (short)f2b(v1.w);
  } else {
#pragma unroll
    for (int i = 0; i < 8; ++i) pack[i] = 0;
  }
  *(s8v*)(xb + base) = pack;
}

// ---- pass 2: W [K=1024][N=1024] f32 -> Wt [N][K] bf16, for q,k,v
__global__ __launch_bounds__(256) void k_transpose_w(const float* __restrict__ Wq,
                                                     const float* __restrict__ Wk,
                                                     const float* __restrict__ Wv,
                                                     u16* __restrict__ Wt) {
  const float* W = (blockIdx.z == 0) ? Wq : ((blockIdx.z == 1) ? Wk : Wv);
  u16* dst = Wt + (size_t)blockIdx.z * 1024 * 1024;
  __shared__ float tile[32][33];
  int n0 = blockIdx.x * 32, k0 = blockIdx.y * 32;
  int tx = threadIdx.x, ty = threadIdx.y;
#pragma unroll
  for (int i = 0; i < 4; ++i)
    tile[ty + i * 8][tx] = W[(size_t)(k0 + ty + i * 8) * 1024 + n0 + tx];
  __syncthreads();
#pragma unroll
  for (int i = 0; i < 4; ++i)
    dst[(size_t)(n0 + ty + i * 8) * 1024 + k0 + tx] = f2b(tile[tx][ty + i * 8]);
}

// ---- pass 3: qkv GEMM, 128x128 tile, BK=32, 3-slot LDS ring, prefetch
// DEPTH 2 with counted vmcnt(8): stages t+1 and t+2 stay in flight while
// computing tile t -> ~2 iterations (>600 cyc) to cover L2/L3 latency.
// 48 KB LDS -> 3 blocks/CU of TLP on top.
// Data-ready: vmcnt(8) leaves only stages t+1,t+2 (4 loads each) outstanding
// -> stage t complete; s_barrier joins all waves -> slot t%3 valid.
// Slot-reuse: stage(t+2) (issued in iter t) overwrites slot (t+2)%3 =
// (t-1)%3, whose readers finished at iter t-1's lgkmcnt(0)+barrier.
__global__ __launch_bounds__(256) void k_gemm_qkv(const u16* __restrict__ xb,
                                                  const u16* __restrict__ Wt,
                                                  u16* __restrict__ Qp,
                                                  u16* __restrict__ Kp,
                                                  u16* __restrict__ Vt) {
  const int zid = blockIdx.z;
  const int m0 = blockIdx.x * 128;
  const int n0 = blockIdx.y * 128;
  const u16* Bg = Wt + (size_t)zid * 1024 * 1024 + (size_t)n0 * 1024;

  // 48 KB: 3 ring slots x (A 128x32 + B 128x32); first 32 KB reused post-loop
  // as the 128x128 V-transpose tile.
  __shared__ __align__(16) u16 shl[24576];

  const int tid = threadIdx.x;
  const int lane = tid & 63;
  const int w = tid >> 6;
  const int wr = w >> 1, wc = w & 1;
  const int lo = lane & 15, g = lane >> 4;

  // staging geometry (validated): rows are 64B (32 u16, 4 chunks of 16B);
  // stored chunk slot = lane&3, source chunk = slot ^ swz(row), swz(r) =
  // (r>>1)&3; read back global chunk g at slot g ^ swz(row).
  const int lrow = lane >> 2;
  const int csrc = (lane & 3) ^ ((lane >> 3) & 3);
  const int rsw = (g ^ ((lo >> 1) & 3)) << 4;

  f4v acc[4][4];
#pragma unroll
  for (int i = 0; i < 4; ++i)
#pragma unroll
    for (int j = 0; j < 4; ++j) {
      f4v z = {0.f, 0.f, 0.f, 0.f};
      acc[i][j] = z;
    }

  auto stage = [&](int tile) {
    u16* Ab = shl + (tile % 3) * 8192;
    u16* Bb = Ab + 4096;
    int kt = tile * 32;
#pragma unroll
    for (int c = 0; c < 2; ++c) {
      int rloc = w * 32 + c * 16 + lrow;
      gll16(xb + (size_t)(m0 + rloc) * 1024 + kt + csrc * 8,
            Ab + (w * 32 + c * 16) * 32);
      gll16(Bg + (size_t)rloc * 1024 + kt + csrc * 8,
            Bb + (w * 32 + c * 16) * 32);
    }
  };

  auto compute = [&](int tile) {
    const u16* Ab = shl + (tile % 3) * 8192;
    const u16* Bb = Ab + 4096;
    s8v af[4], bf[4];
#pragma unroll
    for (int i = 0; i < 4; ++i) {
      int ar = wr * 64 + i * 16 + lo;
      af[i] = *(const s8v*)((const char*)Ab + ar * 64 + rsw);
      int br = wc * 64 + i * 16 + lo;
      bf[i] = *(const s8v*)((const char*)Bb + br * 64 + rsw);
    }
    __builtin_amdgcn_s_setprio(1);
#pragma unroll
    for (int i = 0; i < 4; ++i)
#pragma unroll
      for (int j = 0; j < 4; ++j)
        acc[i][j] = mfma32(af[i], bf[j], acc[i][j]);
    __builtin_amdgcn_s_setprio(0);
  };

#define WBAR(VM)                                            \
  asm volatile("s_waitcnt vmcnt(" VM ")" ::: "memory");     \
  __builtin_amdgcn_s_barrier();                             \
  asm volatile("" ::: "memory");
#define TBAR                                                \
  asm volatile("s_waitcnt lgkmcnt(0)" ::: "memory");        \
  __builtin_amdgcn_s_barrier();                             \
  asm volatile("" ::: "memory");

  stage(0);
  stage(1);
#pragma unroll 1
  for (int t = 0; t < 30; ++t) {
    stage(t + 2);
    WBAR("8")        // stage t complete (t+1, t+2 in flight)
    compute(t);
    TBAR             // slot t%3 readers done -> reusable next iter
  }
  WBAR("4")          // tile 30 ready (31 in flight)
  compute(30);
  TBAR
  WBAR("0")          // tile 31 ready
  compute(31);
  __syncthreads();   // protects LDS reuse by the V epilogue

#undef WBAR
#undef TBAR

  // epilogue: m -> (b, t) -> (s, p); n -> (h, d); combo = (b*3+s)*16+h
  const float esc = (zid == 0) ? QSCALE : 1.0f;
  if (zid != 2) {
    u16* dq = (zid == 0) ? Qp : Kp;
#pragma unroll
    for (int i = 0; i < 4; ++i) {
#pragma unroll
      for (int r = 0; r < 4; ++r) {
        int m = m0 + wr * 64 + i * 16 + g * 4 + r;
        if (m >= 8196) continue;
        int b = m / 4098;
        int t = m - b * 4098;
        int s = t % 3;
        int p = t / 3;
        int cb = (b * 3 + s) * 16;
#pragma unroll
        for (int j = 0; j < 4; ++j) {
          int n = n0 + wc * 64 + j * 16 + lo;
          int h = n >> 6, d = n & 63;
          dq[(size_t)((cb + h) * NBLK + p) * 64 + d] = f2b(acc[i][j][r] * esc);
        }
      }
    }
  } else {
    // V: stage results into LDS tile [m_local][n_local] (32 KB, aliases the
    // ring -- safe after the __syncthreads above), then each thread writes
    // one (n,s) stream of consecutive p as sequential u16 stores.
    u16* tile = shl;
#pragma unroll
    for (int i = 0; i < 4; ++i)
#pragma unroll
      for (int r = 0; r < 4; ++r) {
        int ml = wr * 64 + i * 16 + g * 4 + r;
#pragma unroll
        for (int j = 0; j < 4; ++j) {
          int nl = wc * 64 + j * 16 + lo;
          tile[ml * 128 + nl] = f2b(acc[i][j][r]);
        }
      }
    __syncthreads();
    for (int pair = tid; pair < 384; pair += 256) {
      int nl = pair & 127;
      int s = pair >> 7;               // 0,1 then 2
      int n = n0 + nl;
      int h = n >> 6, d = n & 63;
      for (int b = 0; b < 2; ++b) {
        int mlo = m0 > b * 4098 ? m0 : b * 4098;
        int cap = b * 4098 + 4096;     // t < 4096
        int mhi = (m0 + 128 < cap) ? m0 + 128 : cap;
        if (mlo >= mhi) continue;
        int t_lo = mlo - b * 4098;
        int add = (s - (t_lo % 3) + 3) % 3;
        int t = t_lo + add;
        int tend = mhi - b * 4098;
        u16* dst = Vt + (size_t)(((b * 3 + s) * 16 + h) * 64 + d) * VROW;
        for (; t < tend; t += 3)
          dst[t / 3] = tile[(b * 4098 + t - m0) * 128 + nl];
      }
    }
  }
}

// ---- pass 4: per-(b,h,s) attention over 1366 blocks, single-pass softmax
// (no max subtraction; logits tiny), local logits handled by E-doubling +
// den fixup. den via MFMA with ones-fragment. XCD swizzle: 12 combos/XCD.
// NEW: double-buffered K/V staging with counted vmcnt(2) -- tile jt+1's
// loads fly during tile jt's compute instead of being drained cold.
__global__ __launch_bounds__(256) void k_attn(const u16* __restrict__ Qp,
                                              const u16* __restrict__ Kp,
                                              const u16* __restrict__ Vt,
                                              float* __restrict__ out) {
  const int wg = blockIdx.x;                 // 2112 blocks, 2112%8==0
  const int idx = (wg & 7) * 264 + (wg >> 3);
  const int combo = idx / 22;
  const int q0 = (idx % 22) * 64;
  const int b = combo / 48;
  const int rem = combo - b * 48;
  const int s = rem >> 4;
  const int h = rem & 15;
  const int tid = threadIdx.x, lane = tid & 63, w = tid >> 6;
  const int lo = lane & 15, g = lane >> 4;

  const u16* Qg = Qp + (size_t)combo * (NBLK * 64);
  const u16* Kg = Kp + (size_t)combo * (NBLK * 64);
  const u16* Vg = Vt + (size_t)combo * (64 * VROW);

  // 2 slots x (K 64x64 + V 64x64) = 32 KB
  __shared__ __align__(16) u16 att[16384];

  const int pq_e = q0 + w * 16 + lo;       // query owned by this lane (E rows)
  const int qc = (pq_e < NBLK) ? pq_e : (NBLK - 1);
  s8v qf0 = *(const s8v*)(Qg + (size_t)qc * 64 + g * 8);
  s8v qf1 = *(const s8v*)(Qg + (size_t)qc * 64 + 32 + g * 8);

  s4v onesf;
  onesf[0] = onesf[1] = onesf[2] = onesf[3] = (short)0x3F80;  // bf16 1.0

  f4v oacc[4];
#pragma unroll
  for (int i = 0; i < 4; ++i) {
    f4v z = {0.f, 0.f, 0.f, 0.f};
    oacc[i] = z;
  }
  f4v den_acc = {0.f, 0.f, 0.f, 0.f};

  const int lrow = lane >> 3;
  const int schunk = (lane & 7) ^ lrow;

  auto stage = [&](int jt) {
    int j0 = jt * 64;
    u16* Kl = att + (jt & 1) * 8192;
    u16* Vl = Kl + 4096;
#pragma unroll
    for (int c = 0; c < 2; ++c) {
      int rloc = w * 16 + c * 8 + lrow;
      gll16(Kg + (size_t)(j0 + rloc) * 64 + schunk * 8, Kl + (w * 16 + c * 8) * 64);
      gll16(Vg + (size_t)rloc * VROW + j0 + schunk * 8, Vl + (w * 16 + c * 8) * 64);
    }
  };

  auto compute = [&](int jt) {
    const int j0 = jt * 64;
    const u16* Kl = att + (jt & 1) * 8192;
    const u16* Vl = Kl + 4096;

    // S^T = K * Q^T : sacc[kb] holds S[j = j0+kb*16+g*4+r][q = q0+w*16+lo],
    // already scaled by 0.125*log2e (folded into Q).
    f4v sacc[4];
    __builtin_amdgcn_s_setprio(1);
#pragma unroll
    for (int kb = 0; kb < 4; ++kb) {
      f4v z = {0.f, 0.f, 0.f, 0.f};
      int row = kb * 16 + lo;
      int sw = (row & 7) << 4;
      s8v kf0 = *(const s8v*)((const char*)Kl + row * 128 + ((g * 16) ^ sw));
      s8v kf1 = *(const s8v*)((const char*)Kl + row * 128 + ((64 + g * 16) ^ sw));
      z = mfma32(kf0, qf0, z);
      sacc[kb] = mfma32(kf1, qf1, z);
    }
    __builtin_amdgcn_s_setprio(0);

    // E = exp2(S'); near/edge tiles double where |j-p|<=2 and zero j>=NBLK.
    s4v ef[4];
    const bool special = (j0 >= q0 - 64 && j0 <= q0 + 64) || (j0 + 64 > NBLK);
    if (special) {
#pragma unroll
      for (int kb = 0; kb < 4; ++kb) {
        float e[4];
#pragma unroll
        for (int r = 0; r < 4; ++r) {
          int j = j0 + kb * 16 + g * 4 + r;
          float ev = fexp2(sacc[kb][r]);
          int dd = j - pq_e;
          float fac = (j < NBLK) ? (((dd <= 2) && (dd >= -2)) ? 2.f : 1.f) : 0.f;
          e[r] = ev * fac;
        }
        u32x2 w2;
        w2[0] = cvtpk(e[0], e[1]);
        w2[1] = cvtpk(e[2], e[3]);
        ef[kb] = __builtin_bit_cast(s4v, w2);
      }
    } else {
#pragma unroll
      for (int kb = 0; kb < 4; ++kb) {
        u32x2 w2;
        w2[0] = cvtpk(fexp2(sacc[kb][0]), fexp2(sacc[kb][1]));
        w2[1] = cvtpk(fexp2(sacc[kb][2]), fexp2(sacc[kb][3]));
        ef[kb] = __builtin_bit_cast(s4v, w2);
      }
    }

    // O += E * V ; den += E * ones (all on the MFMA pipe)
    __builtin_amdgcn_s_setprio(1);
#pragma unroll
    for (int kb = 0; kb < 4; ++kb)
      den_acc = mfma16(ef[kb], onesf, den_acc);
#pragma unroll
    for (int db = 0; db < 4; ++db) {
      int row = db * 16 + lo;
      int sw = (row & 7) << 4;
#pragma unroll
      for (int kb = 0; kb < 4; ++kb) {
        s4v vf = *(const s4v*)((const char*)Vl + row * 128 + ((kb * 32 + g * 8) ^ sw));
        oacc[db] = mfma16(ef[kb], vf, oacc[db]);
      }
    }
    __builtin_amdgcn_s_setprio(0);
  };

#define WBAR(VM)                                            \
  asm volatile("s_waitcnt vmcnt(" VM ")" ::: "memory");     \
  __builtin_amdgcn_s_barrier();                             \
  asm volatile("" ::: "memory");
#define TBAR                                                \
  asm volatile("s_waitcnt lgkmcnt(0)" ::: "memory");        \
  __builtin_amdgcn_s_barrier();                             \
  asm volatile("" ::: "memory");

  stage(0);
#pragma unroll 1
  for (int jt = 0; jt < 21; ++jt) {
    stage(jt + 1);
    WBAR("2")          // tile jt ready (jt+1's 2 loads in flight)
    compute(jt);
    TBAR               // slot jt&1 readers done -> reusable next iter
  }
  WBAR("0")            // tile 21 ready
  compute(21);

#undef WBAR
#undef TBAR

  // den_acc[r] = den for q = q0 + w*16 + g*4 + r (identical across lo lanes).
  // Out-of-range local patches contribute exp(0)=1 each.
  const int hbase = h * 64;
#pragma unroll
  for (int r = 0; r < 4; ++r) {
    int pq = q0 + w * 16 + g * 4 + r;
    float dden = den_acc[r];
    dden += (pq == 0 || pq == NBLK - 1) ? 2.f : ((pq == 1 || pq == NBLK - 2) ? 1.f : 0.f);
    float rr = 1.f / dden;
    int t = 3 * pq + s;
    if (pq < NBLK && t < 4096) {
      float* orow = out + ((size_t)b * 4096 + t) * 1024 + hbase;
#pragma unroll
      for (int db = 0; db < 4; ++db)
        orow[db * 16 + lo] = oacc[db][r] * rr;
    }
  }
}

extern "C" void kernel_launch(void* const* d_in, const int* in_sizes, int n_in,
                              void* d_out, int out_size, void* d_ws, size_t ws_size,
                              hipStream_t stream) {
  const float* x  = (const float*)d_in[0];
  const float* Wq = (const float*)d_in[1];
  const float* Wk = (const float*)d_in[2];
  const float* Wv = (const float*)d_in[3];
  float* out = (float*)d_out;

  u16* ws = (u16*)d_ws;
  u16* xb = ws;                        // 8320*1024            = 8,519,680 elems
  u16* Wt = xb + 8519680;              // 3*1024*1024          = 3,145,728
  u16* Qp = Wt + 3145728;              // 96*1366*64           = 8,392,704
  u16* Kp = Qp + 8392704;              // 8,392,704
  u16* Vt = Kp + 8392704;              // 96*64*1376           = 8,454,144 (+256 guard)

  k_convert_x<<<4160, 256, 0, stream>>>(x, xb);
  k_transpose_w<<<dim3(32, 32, 3), dim3(32, 8), 0, stream>>>(Wq, Wk, Wv, Wt);
  // zero V (covers pad columns p in [1366,1376)) + guard region after it, so
  // masked over-reads in the attention staging are always finite.
  hipMemsetAsync(Vt, 0, (size_t)(8454144 + 256) * sizeof(u16), stream);
  k_gemm_qkv<<<dim3(65, 8, 3), 256, 0, stream>>>(xb, Wt, Qp, Kp, Vt);
  k_attn<<<dim3(2112), 256, 0, stream>>>(Qp, Kp, Vt, out);
}

// Round 9
// 223.199 us; speedup vs baseline: 1.0069x; 1.0069x over previous
//
#include <hip/hip_runtime.h>
#include <hip/hip_bf16.h>

typedef unsigned int u32;
typedef unsigned short u16;
typedef short s8v __attribute__((ext_vector_type(8)));
typedef short s4v __attribute__((ext_vector_type(4)));
typedef float f4v __attribute__((ext_vector_type(4)));
typedef float f16v __attribute__((ext_vector_type(16)));
typedef u32 u32x2 __attribute__((ext_vector_type(2)));

// Problem constants: B=2, L=4096, D=1024, HEADS=16, KEY=SPH=64, STEP=3
// new_len=4098, blocks P=1366, combos = B*3*H = 96
#define NBLK 1366
#define VROW 1376   // padded V row stride (16B aligned)
#define QSCALE 0.18033688011112042f   // 0.125 * log2(e), folded into Q

__device__ __forceinline__ u16 f2b(float f) {
  u32 u = __builtin_bit_cast(u32, f);
  u = (u + 0x7FFFu + ((u >> 16) & 1u)) >> 16;
  return (u16)u;
}

__device__ __forceinline__ u32 cvtpk(float a, float b) {
  u32 r;
  asm("v_cvt_pk_bf16_f32 %0, %1, %2" : "=v"(r) : "v"(a), "v"(b));
  return r;
}

__device__ __forceinline__ float fexp2(float x) {
#if defined(__has_builtin)
#if __has_builtin(__builtin_amdgcn_exp2f)
  return __builtin_amdgcn_exp2f(x);
#define FEXP2_DONE 1
#endif
#endif
#ifndef FEXP2_DONE
  float r;
  asm("v_exp_f32 %0, %1" : "=v"(r) : "v"(x));
  return r;
#endif
}

__device__ __forceinline__ void gll16(const void* g, void* l) {
  __builtin_amdgcn_global_load_lds(
      (const __attribute__((address_space(1))) u32*)g,
      (__attribute__((address_space(3))) u32*)l, 16, 0, 0);
}

__device__ __forceinline__ f4v mfma32(s8v a, s8v b, f4v c) {
  return __builtin_amdgcn_mfma_f32_16x16x32_bf16(a, b, c, 0, 0, 0);
}

__device__ __forceinline__ f16v mfma3216(s8v a, s8v b, f16v c) {
  return __builtin_amdgcn_mfma_f32_32x32x16_bf16(a, b, c, 0, 0, 0);
}

__device__ __forceinline__ f16v mfma3208(s4v a, s4v b, f16v c) {
#if defined(__has_builtin)
#if __has_builtin(__builtin_amdgcn_mfma_f32_32x32x8bf16_1k)
#define MFMA3208_BUILTIN 1
#endif
#endif
#ifdef MFMA3208_BUILTIN
  return __builtin_amdgcn_mfma_f32_32x32x8bf16_1k(a, b, c, 0, 0, 0);
#else
  f16v d;
  asm("v_mfma_f32_32x32x8_bf16 %0, %1, %2, %3" : "=v"(d) : "v"(a), "v"(b), "v"(c));
  return d;
#endif
}

// ---- pass 1 (fused prep): blocks [0,4160): x f32 -> xb bf16 (zero pads);
// blocks [4160,7232): W transpose+convert; blocks [7232,7257): V pad-zero.
__global__ __launch_bounds__(256) void k_prep(const float* __restrict__ x,
                                              const float* __restrict__ Wq,
                                              const float* __restrict__ Wk,
                                              const float* __restrict__ Wv,
                                              u16* __restrict__ xb,
                                              u16* __restrict__ Wt,
                                              u16* __restrict__ Vt) {
  const int bid = blockIdx.x;
  const int tid = threadIdx.x;
  if (bid < 4160) {
    long base = ((long)bid * 256 + tid) * 8;
    if (base >= 8320L * 1024L) return;
    int m = (int)(base >> 10);
    int c = (int)(base & 1023);
    int b = m / 4098;
    int t = m - b * 4098;
    s8v pack;
    if (m < 8196 && t < 4096) {
      const float* src = x + ((size_t)b * 4096 + t) * 1024 + c;
      float4 v0 = *(const float4*)(src);
      float4 v1 = *(const float4*)(src + 4);
      pack[0] = (short)f2b(v0.x); pack[1] = (short)f2b(v0.y);
      pack[2] = (short)f2b(v0.z); pack[3] = (short)f2b(v0.w);
      pack[4] = (short)f2b(v1.x); pack[5] = (short)f2b(v1.y);
      pack[6] = (short)f2b(v1.z); pack[7] = (short)f2b(v1.w);
    } else {
#pragma unroll
      for (int i = 0; i < 8; ++i) pack[i] = 0;
    }
    *(s8v*)(xb + base) = pack;
  } else if (bid < 7232) {
    __shared__ float tile[32][33];
    int bid3 = bid - 4160;
    int z = bid3 >> 10;
    int rem = bid3 & 1023;
    const float* W = (z == 0) ? Wq : ((z == 1) ? Wk : Wv);
    u16* dst = Wt + (size_t)z * 1024 * 1024;
    int n0 = (rem & 31) * 32, k0 = (rem >> 5) * 32;
    int tx = tid & 31, ty = tid >> 5;
#pragma unroll
    for (int i = 0; i < 4; ++i)
      tile[ty + i * 8][tx] = W[(size_t)(k0 + ty + i * 8) * 1024 + n0 + tx];
    __syncthreads();
#pragma unroll
    for (int i = 0; i < 4; ++i)
      dst[(size_t)(n0 + ty + i * 8) * 1024 + k0 + tx] = f2b(tile[tx][ty + i * 8]);
  } else {
    // zero V pad columns p in [1366,1376) for all 6144 (combo,d) rows + guard
    int gidx = (bid - 7232) * 256 + tid;
    if (gidx < 6144) {
      u16* dst = Vt + (size_t)gidx * VROW + NBLK;
#pragma unroll
      for (int i = 0; i < 10; ++i) dst[i] = 0;
    } else if (gidx < 6400) {
      Vt[(size_t)6144 * VROW + (gidx - 6144)] = 0;
    }
  }
}

// ---- pass 2: qkv GEMM (R7 structure, unchanged): 128x128 tile, BK=32,
// 2-slot LDS ring with counted vmcnt(4); V transposed through LDS epilogue.
__global__ __launch_bounds__(256) void k_gemm_qkv(const u16* __restrict__ xb,
                                                  const u16* __restrict__ Wt,
                                                  u16* __restrict__ Qp,
                                                  u16* __restrict__ Kp,
                                                  u16* __restrict__ Vt) {
  const int zid = blockIdx.z;
  const int m0 = blockIdx.x * 128;
  const int n0 = blockIdx.y * 128;
  const u16* Bg = Wt + (size_t)zid * 1024 * 1024 + (size_t)n0 * 1024;

  __shared__ __align__(16) u16 shl[16384];
  u16* A0 = shl;
  u16* A1 = shl + 4096;
  u16* B0 = shl + 8192;
  u16* B1 = shl + 12288;

  const int tid = threadIdx.x;
  const int lane = tid & 63;
  const int w = tid >> 6;
  const int wr = w >> 1, wc = w & 1;
  const int lo = lane & 15, g = lane >> 4;

  const int lrow = lane >> 2;
  const int csrc = (lane & 3) ^ ((lane >> 3) & 3);
  const int rsw = (g ^ ((lo >> 1) & 3)) << 4;

  f4v acc[4][4];
#pragma unroll
  for (int i = 0; i < 4; ++i)
#pragma unroll
    for (int j = 0; j < 4; ++j) {
      f4v z = {0.f, 0.f, 0.f, 0.f};
      acc[i][j] = z;
    }

  auto stage = [&](int kt, u16* Ab, u16* Bb) {
#pragma unroll
    for (int c = 0; c < 2; ++c) {
      int rloc = w * 32 + c * 16 + lrow;
      gll16(xb + (size_t)(m0 + rloc) * 1024 + kt + csrc * 8,
            Ab + (w * 32 + c * 16) * 32);
      gll16(Bg + (size_t)rloc * 1024 + kt + csrc * 8,
            Bb + (w * 32 + c * 16) * 32);
    }
  };

  auto compute = [&](const u16* Ab, const u16* Bb) {
    s8v af[4], bf[4];
#pragma unroll
    for (int i = 0; i < 4; ++i) {
      int ar = wr * 64 + i * 16 + lo;
      af[i] = *(const s8v*)((const char*)Ab + ar * 64 + rsw);
      int br = wc * 64 + i * 16 + lo;
      bf[i] = *(const s8v*)((const char*)Bb + br * 64 + rsw);
    }
    __builtin_amdgcn_s_setprio(1);
#pragma unroll
    for (int i = 0; i < 4; ++i)
#pragma unroll
      for (int j = 0; j < 4; ++j)
        acc[i][j] = mfma32(af[i], bf[j], acc[i][j]);
    __builtin_amdgcn_s_setprio(0);
  };

#define BAR_VM4                                             \
  asm volatile("s_waitcnt vmcnt(4)" ::: "memory");          \
  __builtin_amdgcn_s_barrier();                             \
  asm volatile("" ::: "memory");
#define BAR_LGKM                                            \
  asm volatile("s_waitcnt lgkmcnt(0)" ::: "memory");        \
  __builtin_amdgcn_s_barrier();                             \
  asm volatile("" ::: "memory");

  stage(0, A0, B0);
#pragma unroll 1
  for (int kk = 0; kk < 15; ++kk) {
    int kt = kk * 64;
    stage(kt + 32, A1, B1);
    BAR_VM4
    compute(A0, B0);
    BAR_LGKM
    stage(kt + 64, A0, B0);
    BAR_VM4
    compute(A1, B1);
    BAR_LGKM
  }
  stage(31 * 32, A1, B1);
  BAR_VM4
  compute(A0, B0);
  BAR_LGKM
  asm volatile("s_waitcnt vmcnt(0)" ::: "memory");
  __builtin_amdgcn_s_barrier();
  asm volatile("" ::: "memory");
  compute(A1, B1);
  __syncthreads();

#undef BAR_VM4
#undef BAR_LGKM

  const float esc = (zid == 0) ? QSCALE : 1.0f;
  if (zid != 2) {
    u16* dq = (zid == 0) ? Qp : Kp;
#pragma unroll
    for (int i = 0; i < 4; ++i) {
#pragma unroll
      for (int r = 0; r < 4; ++r) {
        int m = m0 + wr * 64 + i * 16 + g * 4 + r;
        if (m >= 8196) continue;
        int b = m / 4098;
        int t = m - b * 4098;
        int s = t % 3;
        int p = t / 3;
        int cb = (b * 3 + s) * 16;
#pragma unroll
        for (int j = 0; j < 4; ++j) {
          int n = n0 + wc * 64 + j * 16 + lo;
          int h = n >> 6, d = n & 63;
          dq[(size_t)((cb + h) * NBLK + p) * 64 + d] = f2b(acc[i][j][r] * esc);
        }
      }
    }
  } else {
    u16* tile = shl;
#pragma unroll
    for (int i = 0; i < 4; ++i)
#pragma unroll
      for (int r = 0; r < 4; ++r) {
        int ml = wr * 64 + i * 16 + g * 4 + r;
#pragma unroll
        for (int j = 0; j < 4; ++j) {
          int nl = wc * 64 + j * 16 + lo;
          tile[ml * 128 + nl] = f2b(acc[i][j][r]);
        }
      }
    __syncthreads();
    for (int pair = tid; pair < 384; pair += 256) {
      int nl = pair & 127;
      int s = pair >> 7;
      int n = n0 + nl;
      int h = n >> 6, d = n & 63;
      for (int b = 0; b < 2; ++b) {
        int mlo = m0 > b * 4098 ? m0 : b * 4098;
        int cap = b * 4098 + 4096;
        int mhi = (m0 + 128 < cap) ? m0 + 128 : cap;
        if (mlo >= mhi) continue;
        int t_lo = mlo - b * 4098;
        int add = (s - (t_lo % 3) + 3) % 3;
        int t = t_lo + add;
        int tend = mhi - b * 4098;
        u16* dst = Vt + (size_t)(((b * 3 + s) * 16 + h) * 64 + d) * VROW;
        for (; t < tend; t += 3)
          dst[t / 3] = tile[(b * 4098 + t - m0) * 128 + nl];
      }
    }
  }
}

// ---- pass 3: attention v2 -- 32x32 MFMA, q=32/wave (block = 128 q), 1056
// blocks (half the LDS traffic of v1), ADD-rotation LDS swizzle (conflict-
// free for b128 K-frags and b64 V-frags). Single-pass softmax (no max-sub),
// local-logit doubling + den fixup; den via mfma(E, ones) so den rows align
// with oacc rows.  S^T = K*Q^T C-layout: lane q = l&31, j = crow(r, l>>5);
// crow(r,hi) = (r&3)+8*(r>>2)+4*hi.  PV A-frag(32x32x8): reg ks*4+idx ==
// E[q][j=ks*8+hi*4+idx] -- direct cvtpk from sacc, no shuffles.
__global__ __launch_bounds__(256, 4) void k_attn(const u16* __restrict__ Qp,
                                                 const u16* __restrict__ Kp,
                                                 const u16* __restrict__ Vt,
                                                 float* __restrict__ out) {
  const int wg = blockIdx.x;                 // 1056 = 8*132
  const int idx = (wg & 7) * 132 + (wg >> 3);
  const int combo = idx / 11;
  const int qb = idx - combo * 11;           // q-block [0,11), 128 q each
  const int b = combo / 48;
  const int rem = combo - b * 48;
  const int s = rem >> 4;
  const int h = rem & 15;
  const int tid = threadIdx.x, lane = tid & 63, w = tid >> 6;
  const int lq = lane & 31, lh = lane >> 5;

  const u16* Qg = Qp + (size_t)combo * (NBLK * 64);
  const u16* Kg = Kp + (size_t)combo * (NBLK * 64);
  const u16* Vg = Vt + (size_t)combo * (64 * VROW);

  __shared__ __align__(16) u16 Kl[64 * 64];  // [j 64][k 64]
  __shared__ __align__(16) u16 Vl[64 * 64];  // [d 64][j 64]

  const int qg = qb * 128 + w * 32 + lq;     // this lane's q
  const int qc = (qg < NBLK) ? qg : (NBLK - 1);
  s8v qf[4];
#pragma unroll
  for (int ss = 0; ss < 4; ++ss)
    qf[ss] = *(const s8v*)(Qg + (size_t)qc * 64 + ss * 16 + lh * 8);

  s4v onesf;
  onesf[0] = onesf[1] = onesf[2] = onesf[3] = (short)0x3F80;  // bf16 1.0

  f16v oacc0, oacc1, den_acc;
#pragma unroll
  for (int i = 0; i < 16; ++i) { oacc0[i] = 0.f; oacc1[i] = 0.f; den_acc[i] = 0.f; }

  // staging: rows of 128B (8 chunks of 16B); dest linear lane*16B; source
  // chunk = (slot - row%8) mod 8  (ADD-rotation, inverse on read)
  const int srow8 = lane >> 3;
  const int schunk = ((lane & 7) - srow8) & 7;
  const int qmin = qb * 128;

  for (int j0 = 0; j0 < NBLK; j0 += 64) {
    __syncthreads();
#pragma unroll
    for (int c = 0; c < 2; ++c) {
      int rbase = c * 32 + w * 8;
      gll16(Kg + (size_t)(j0 + rbase + srow8) * 64 + schunk * 8, Kl + rbase * 64);
      gll16(Vg + (size_t)(rbase + srow8) * VROW + j0 + schunk * 8, Vl + rbase * 64);
    }
    __syncthreads();

    const bool special = ((j0 <= qmin + 129) && (j0 + 65 >= qmin)) || (j0 + 64 > NBLK);
    s4v ef[8];
#pragma unroll
    for (int jb = 0; jb < 2; ++jb) {
      f16v sacc;
#pragma unroll
      for (int i = 0; i < 16; ++i) sacc[i] = 0.f;
      __builtin_amdgcn_s_setprio(1);
#pragma unroll
      for (int ss = 0; ss < 4; ++ss) {
        s8v kf = *(const s8v*)((const char*)Kl + (jb * 32 + lq) * 128 +
                               ((((ss * 2 + lh) + (lq & 7)) & 7) << 4));
        sacc = mfma3216(kf, qf[ss], sacc);
      }
      __builtin_amdgcn_s_setprio(0);

      if (special) {
        float e[16];
#pragma unroll
        for (int r = 0; r < 16; ++r) {
          int j = j0 + jb * 32 + (r & 3) + 8 * (r >> 2) + 4 * lh;
          float ev = fexp2(sacc[r]);
          int dd = j - qg;
          float fac = (j < NBLK) ? (((dd <= 2) && (dd >= -2)) ? 2.f : 1.f) : 0.f;
          e[r] = ev * fac;
        }
#pragma unroll
        for (int k4 = 0; k4 < 4; ++k4) {
          u32x2 w2;
          w2[0] = cvtpk(e[k4 * 4 + 0], e[k4 * 4 + 1]);
          w2[1] = cvtpk(e[k4 * 4 + 2], e[k4 * 4 + 3]);
          ef[jb * 4 + k4] = __builtin_bit_cast(s4v, w2);
        }
      } else {
#pragma unroll
        for (int k4 = 0; k4 < 4; ++k4) {
          u32x2 w2;
          w2[0] = cvtpk(fexp2(sacc[k4 * 4 + 0]), fexp2(sacc[k4 * 4 + 1]));
          w2[1] = cvtpk(fexp2(sacc[k4 * 4 + 2]), fexp2(sacc[k4 * 4 + 3]));
          ef[jb * 4 + k4] = __builtin_bit_cast(s4v, w2);
        }
      }
    }

    __builtin_amdgcn_s_setprio(1);
#pragma unroll
    for (int ks = 0; ks < 8; ++ks)
      den_acc = mfma3208(ef[ks], onesf, den_acc);
#pragma unroll
    for (int ks = 0; ks < 8; ++ks) {
      const char* vb = (const char*)Vl + lq * 128 +
                       (((ks + (lq & 7)) & 7) << 4) + lh * 8;
      s4v vf0 = *(const s4v*)(vb);
      s4v vf1 = *(const s4v*)(vb + 32 * 128);
      oacc0 = mfma3208(ef[ks], vf0, oacc0);
      oacc1 = mfma3208(ef[ks], vf1, oacc1);
    }
    __builtin_amdgcn_s_setprio(0);
  }

  // epilogue: oacc rows q = crow(r,lh), cols d = db2*32+lq; den aligned.
  const int hbase = h * 64;
#pragma unroll
  for (int r = 0; r < 16; ++r) {
    int q = qb * 128 + w * 32 + (r & 3) + 8 * (r >> 2) + 4 * lh;
    float dden = den_acc[r];
    dden += (q == 0 || q == NBLK - 1) ? 2.f : ((q == 1 || q == NBLK - 2) ? 1.f : 0.f);
    float rr = 1.f / dden;
    int t = 3 * q + s;
    if (q < NBLK && t < 4096) {
      float* orow = out + ((size_t)b * 4096 + t) * 1024 + hbase + lq;
      orow[0] = oacc0[r] * rr;
      orow[32] = oacc1[r] * rr;
    }
  }
}

extern "C" void kernel_launch(void* const* d_in, const int* in_sizes, int n_in,
                              void* d_out, int out_size, void* d_ws, size_t ws_size,
                              hipStream_t stream) {
  const float* x  = (const float*)d_in[0];
  const float* Wq = (const float*)d_in[1];
  const float* Wk = (const float*)d_in[2];
  const float* Wv = (const float*)d_in[3];
  float* out = (float*)d_out;

  u16* ws = (u16*)d_ws;
  u16* xb = ws;                        // 8320*1024            = 8,519,680 elems
  u16* Wt = xb + 8519680;              // 3*1024*1024          = 3,145,728
  u16* Qp = Wt + 3145728;              // 96*1366*64           = 8,392,704
  u16* Kp = Qp + 8392704;              // 8,392,704
  u16* Vt = Kp + 8392704;              // 96*64*1376           = 8,454,144 (+256 guard)

  k_prep<<<dim3(7257), 256, 0, stream>>>(x, Wq, Wk, Wv, xb, Wt, Vt);
  k_gemm_qkv<<<dim3(65, 8, 3), 256, 0, stream>>>(xb, Wt, Qp, Kp, Vt);
  k_attn<<<dim3(1056), 256, 0, stream>>>(Qp, Kp, Vt, out);
}

// Round 10
// 217.630 us; speedup vs baseline: 1.0327x; 1.0256x over previous
//
#include <hip/hip_runtime.h>
#include <hip/hip_bf16.h>

typedef unsigned int u32;
typedef unsigned short u16;
typedef short s8v __attribute__((ext_vector_type(8)));
typedef short s4v __attribute__((ext_vector_type(4)));
typedef float f4v __attribute__((ext_vector_type(4)));
typedef float f16v __attribute__((ext_vector_type(16)));
typedef u32 u32x2 __attribute__((ext_vector_type(2)));

// Problem constants: B=2, L=4096, D=1024, HEADS=16, KEY=SPH=64, STEP=3
// new_len=4098, blocks P=1366, combos = B*3*H = 96
#define NBLK 1366
#define VROW 1376   // padded V row stride (16B aligned)
#define QSCALE 0.18033688011112042f   // 0.125 * log2(e), folded into Q

__device__ __forceinline__ u16 f2b(float f) {
  u32 u = __builtin_bit_cast(u32, f);
  u = (u + 0x7FFFu + ((u >> 16) & 1u)) >> 16;
  return (u16)u;
}

__device__ __forceinline__ u32 cvtpk(float a, float b) {
  u32 r;
  asm("v_cvt_pk_bf16_f32 %0, %1, %2" : "=v"(r) : "v"(a), "v"(b));
  return r;
}

__device__ __forceinline__ float fexp2(float x) {
#if defined(__has_builtin)
#if __has_builtin(__builtin_amdgcn_exp2f)
  return __builtin_amdgcn_exp2f(x);
#define FEXP2_DONE 1
#endif
#endif
#ifndef FEXP2_DONE
  float r;
  asm("v_exp_f32 %0, %1" : "=v"(r) : "v"(x));
  return r;
#endif
}

__device__ __forceinline__ void gll16(const void* g, void* l) {
  __builtin_amdgcn_global_load_lds(
      (const __attribute__((address_space(1))) u32*)g,
      (__attribute__((address_space(3))) u32*)l, 16, 0, 0);
}

__device__ __forceinline__ f4v mfma32(s8v a, s8v b, f4v c) {
  return __builtin_amdgcn_mfma_f32_16x16x32_bf16(a, b, c, 0, 0, 0);
}

__device__ __forceinline__ f16v mfma3216(s8v a, s8v b, f16v c) {
  return __builtin_amdgcn_mfma_f32_32x32x16_bf16(a, b, c, 0, 0, 0);
}

__device__ __forceinline__ f16v mfma3208(s4v a, s4v b, f16v c) {
#if defined(__has_builtin)
#if __has_builtin(__builtin_amdgcn_mfma_f32_32x32x8bf16_1k)
#define MFMA3208_BUILTIN 1
#endif
#endif
#ifdef MFMA3208_BUILTIN
  return __builtin_amdgcn_mfma_f32_32x32x8bf16_1k(a, b, c, 0, 0, 0);
#else
  f16v d;
  asm("v_mfma_f32_32x32x8_bf16 %0, %1, %2, %3" : "=v"(d) : "v"(a), "v"(b), "v"(c));
  return d;
#endif
}

__device__ __forceinline__ s4v lo4(s8v v) {
  return __builtin_shufflevector(v, v, 0, 1, 2, 3);
}
__device__ __forceinline__ s4v hi4(s8v v) {
  return __builtin_shufflevector(v, v, 4, 5, 6, 7);
}

// ---- pass 1 (fused prep): blocks [0,4160): x f32 -> xb bf16 (zero pads);
// blocks [4160,7232): W transpose+convert; blocks [7232,7257): V pad-zero.
__global__ __launch_bounds__(256) void k_prep(const float* __restrict__ x,
                                              const float* __restrict__ Wq,
                                              const float* __restrict__ Wk,
                                              const float* __restrict__ Wv,
                                              u16* __restrict__ xb,
                                              u16* __restrict__ Wt,
                                              u16* __restrict__ Vt) {
  const int bid = blockIdx.x;
  const int tid = threadIdx.x;
  if (bid < 4160) {
    long base = ((long)bid * 256 + tid) * 8;
    if (base >= 8320L * 1024L) return;
    int m = (int)(base >> 10);
    int c = (int)(base & 1023);
    int b = m / 4098;
    int t = m - b * 4098;
    s8v pack;
    if (m < 8196 && t < 4096) {
      const float* src = x + ((size_t)b * 4096 + t) * 1024 + c;
      float4 v0 = *(const float4*)(src);
      float4 v1 = *(const float4*)(src + 4);
      pack[0] = (short)f2b(v0.x); pack[1] = (short)f2b(v0.y);
      pack[2] = (short)f2b(v0.z); pack[3] = (short)f2b(v0.w);
      pack[4] = (short)f2b(v1.x); pack[5] = (short)f2b(v1.y);
      pack[6] = (short)f2b(v1.z); pack[7] = (short)f2b(v1.w);
    } else {
#pragma unroll
      for (int i = 0; i < 8; ++i) pack[i] = 0;
    }
    *(s8v*)(xb + base) = pack;
  } else if (bid < 7232) {
    __shared__ float tile[32][33];
    int bid3 = bid - 4160;
    int z = bid3 >> 10;
    int rem = bid3 & 1023;
    const float* W = (z == 0) ? Wq : ((z == 1) ? Wk : Wv);
    u16* dst = Wt + (size_t)z * 1024 * 1024;
    int n0 = (rem & 31) * 32, k0 = (rem >> 5) * 32;
    int tx = tid & 31, ty = tid >> 5;
#pragma unroll
    for (int i = 0; i < 4; ++i)
      tile[ty + i * 8][tx] = W[(size_t)(k0 + ty + i * 8) * 1024 + n0 + tx];
    __syncthreads();
#pragma unroll
    for (int i = 0; i < 4; ++i)
      dst[(size_t)(n0 + ty + i * 8) * 1024 + k0 + tx] = f2b(tile[tx][ty + i * 8]);
  } else {
    // zero V pad columns p in [1366,1376) for all 6144 (combo,d) rows + guard
    int gidx = (bid - 7232) * 256 + tid;
    if (gidx < 6144) {
      u16* dst = Vt + (size_t)gidx * VROW + NBLK;
#pragma unroll
      for (int i = 0; i < 10; ++i) dst[i] = 0;
    } else if (gidx < 6400) {
      Vt[(size_t)6144 * VROW + (gidx - 6144)] = 0;
    }
  }
}

// ---- pass 2: qkv GEMM (R7 structure, unchanged -- session best): 128x128
// tile, BK=32, 2-slot LDS ring with counted vmcnt(4); V transposed through
// LDS epilogue with sequential p-runs.
__global__ __launch_bounds__(256) void k_gemm_qkv(const u16* __restrict__ xb,
                                                  const u16* __restrict__ Wt,
                                                  u16* __restrict__ Qp,
                                                  u16* __restrict__ Kp,
                                                  u16* __restrict__ Vt) {
  const int zid = blockIdx.z;
  const int m0 = blockIdx.x * 128;
  const int n0 = blockIdx.y * 128;
  const u16* Bg = Wt + (size_t)zid * 1024 * 1024 + (size_t)n0 * 1024;

  __shared__ __align__(16) u16 shl[16384];
  u16* A0 = shl;
  u16* A1 = shl + 4096;
  u16* B0 = shl + 8192;
  u16* B1 = shl + 12288;

  const int tid = threadIdx.x;
  const int lane = tid & 63;
  const int w = tid >> 6;
  const int wr = w >> 1, wc = w & 1;
  const int lo = lane & 15, g = lane >> 4;

  const int lrow = lane >> 2;
  const int csrc = (lane & 3) ^ ((lane >> 3) & 3);
  const int rsw = (g ^ ((lo >> 1) & 3)) << 4;

  f4v acc[4][4];
#pragma unroll
  for (int i = 0; i < 4; ++i)
#pragma unroll
    for (int j = 0; j < 4; ++j) {
      f4v z = {0.f, 0.f, 0.f, 0.f};
      acc[i][j] = z;
    }

  auto stage = [&](int kt, u16* Ab, u16* Bb) {
#pragma unroll
    for (int c = 0; c < 2; ++c) {
      int rloc = w * 32 + c * 16 + lrow;
      gll16(xb + (size_t)(m0 + rloc) * 1024 + kt + csrc * 8,
            Ab + (w * 32 + c * 16) * 32);
      gll16(Bg + (size_t)rloc * 1024 + kt + csrc * 8,
            Bb + (w * 32 + c * 16) * 32);
    }
  };

  auto compute = [&](const u16* Ab, const u16* Bb) {
    s8v af[4], bf[4];
#pragma unroll
    for (int i = 0; i < 4; ++i) {
      int ar = wr * 64 + i * 16 + lo;
      af[i] = *(const s8v*)((const char*)Ab + ar * 64 + rsw);
      int br = wc * 64 + i * 16 + lo;
      bf[i] = *(const s8v*)((const char*)Bb + br * 64 + rsw);
    }
    __builtin_amdgcn_s_setprio(1);
#pragma unroll
    for (int i = 0; i < 4; ++i)
#pragma unroll
      for (int j = 0; j < 4; ++j)
        acc[i][j] = mfma32(af[i], bf[j], acc[i][j]);
    __builtin_amdgcn_s_setprio(0);
  };

#define BAR_VM4                                             \
  asm volatile("s_waitcnt vmcnt(4)" ::: "memory");          \
  __builtin_amdgcn_s_barrier();                             \
  asm volatile("" ::: "memory");
#define BAR_LGKM                                            \
  asm volatile("s_waitcnt lgkmcnt(0)" ::: "memory");        \
  __builtin_amdgcn_s_barrier();                             \
  asm volatile("" ::: "memory");

  stage(0, A0, B0);
#pragma unroll 1
  for (int kk = 0; kk < 15; ++kk) {
    int kt = kk * 64;
    stage(kt + 32, A1, B1);
    BAR_VM4
    compute(A0, B0);
    BAR_LGKM
    stage(kt + 64, A0, B0);
    BAR_VM4
    compute(A1, B1);
    BAR_LGKM
  }
  stage(31 * 32, A1, B1);
  BAR_VM4
  compute(A0, B0);
  BAR_LGKM
  asm volatile("s_waitcnt vmcnt(0)" ::: "memory");
  __builtin_amdgcn_s_barrier();
  asm volatile("" ::: "memory");
  compute(A1, B1);
  __syncthreads();

#undef BAR_VM4
#undef BAR_LGKM

  const float esc = (zid == 0) ? QSCALE : 1.0f;
  if (zid != 2) {
    u16* dq = (zid == 0) ? Qp : Kp;
#pragma unroll
    for (int i = 0; i < 4; ++i) {
#pragma unroll
      for (int r = 0; r < 4; ++r) {
        int m = m0 + wr * 64 + i * 16 + g * 4 + r;
        if (m >= 8196) continue;
        int b = m / 4098;
        int t = m - b * 4098;
        int s = t % 3;
        int p = t / 3;
        int cb = (b * 3 + s) * 16;
#pragma unroll
        for (int j = 0; j < 4; ++j) {
          int n = n0 + wc * 64 + j * 16 + lo;
          int h = n >> 6, d = n & 63;
          dq[(size_t)((cb + h) * NBLK + p) * 64 + d] = f2b(acc[i][j][r] * esc);
        }
      }
    }
  } else {
    u16* tile = shl;
#pragma unroll
    for (int i = 0; i < 4; ++i)
#pragma unroll
      for (int r = 0; r < 4; ++r) {
        int ml = wr * 64 + i * 16 + g * 4 + r;
#pragma unroll
        for (int j = 0; j < 4; ++j) {
          int nl = wc * 64 + j * 16 + lo;
          tile[ml * 128 + nl] = f2b(acc[i][j][r]);
        }
      }
    __syncthreads();
    for (int pair = tid; pair < 384; pair += 256) {
      int nl = pair & 127;
      int s = pair >> 7;
      int n = n0 + nl;
      int h = n >> 6, d = n & 63;
      for (int b = 0; b < 2; ++b) {
        int mlo = m0 > b * 4098 ? m0 : b * 4098;
        int cap = b * 4098 + 4096;
        int mhi = (m0 + 128 < cap) ? m0 + 128 : cap;
        if (mlo >= mhi) continue;
        int t_lo = mlo - b * 4098;
        int add = (s - (t_lo % 3) + 3) % 3;
        int t = t_lo + add;
        int tend = mhi - b * 4098;
        u16* dst = Vt + (size_t)(((b * 3 + s) * 16 + h) * 64 + d) * VROW;
        for (; t < tend; t += 3)
          dst[t / 3] = tile[(b * 4098 + t - m0) * 128 + nl];
      }
    }
  }
}

// ---- pass 3: attention v3 -- 32x32 MFMA (q=32/wave, halved LDS volume) +
// CONFLICT-FREE reads via lh-split half-buffers with 72B padded rows
// (bank start = 18*lq mod 32 -> 2-way only), reg-staged (T14) double buffer,
// ONE barrier per j-tile, loads for tile t+2 in flight across the barrier.
// Ring safety: writes of tile t+1 (slot (t+1)&1) happen after the iter-t
// barrier, which each wave passes only after lgkmcnt(0) following its
// compute(t-1) reads of that same slot.
__global__ __launch_bounds__(256, 4) void k_attn(const u16* __restrict__ Qp,
                                                 const u16* __restrict__ Kp,
                                                 const u16* __restrict__ Vt,
                                                 float* __restrict__ out) {
  const int wg = blockIdx.x;                 // 1056 = 8*132
  const int idx = (wg & 7) * 132 + (wg >> 3);
  const int combo = idx / 11;
  const int qb = idx - combo * 11;           // q-block [0,11), 128 q each
  const int b = combo / 48;
  const int rem = combo - b * 48;
  const int s = rem >> 4;
  const int h = rem & 15;
  const int tid = threadIdx.x, lane = tid & 63, w = tid >> 6;
  const int lq = lane & 31, lh = lane >> 5;

  const u16* Qg = Qp + (size_t)combo * (NBLK * 64);
  const u16* Kg = Kp + (size_t)combo * (NBLK * 64);
  const u16* Vg = Vt + (size_t)combo * (64 * VROW);

  // [slot][buf: K_lh0, K_lh1, V_lh0, V_lh1][64 rows * 36 u16 (72B: 64B+8B pad)]
  __shared__ __align__(16) u16 att[2][4][64 * 36];

  const int qg = qb * 128 + w * 32 + lq;     // this lane's q
  const int qc = (qg < NBLK) ? qg : (NBLK - 1);
  s8v qf[4];
#pragma unroll
  for (int ss = 0; ss < 4; ++ss)
    qf[ss] = *(const s8v*)(Qg + (size_t)qc * 64 + ss * 16 + lh * 8);

  s4v onesf;
  onesf[0] = onesf[1] = onesf[2] = onesf[3] = (short)0x3F80;  // bf16 1.0

  f16v oacc0, oacc1, den_acc;
#pragma unroll
  for (int i = 0; i < 16; ++i) { oacc0[i] = 0.f; oacc1[i] = 0.f; den_acc[i] = 0.f; }

  // staging: thread owns global 16B chunks c0=2*tid, c0+1 of both K and V
  // tiles (row = c0>>3 in [0,64), ch = c0&7 even).
  const int srow = tid >> 2;                 // (2*tid)>>3
  const int sch = (tid & 3) * 2;             // even chunk
  const int ssub = (tid & 3) * 8;            // (ch>>1)*8 u16 within half-row
  s8v kr0, kr1, vr0, vr1;

  auto load_regs = [&](int jt) {
    const int j0 = jt * 64;
    const u16* kp = Kg + (size_t)(j0 + srow) * 64 + sch * 8;
    kr0 = *(const s8v*)(kp);
    kr1 = *(const s8v*)(kp + 8);
    const u16* vp = Vg + (size_t)srow * VROW + j0 + sch * 8;
    vr0 = *(const s8v*)(vp);
    vr1 = *(const s8v*)(vp + 8);
  };

  auto stage_write = [&](int slot) {
    u16* K0 = att[slot][0];
    u16* K1 = att[slot][1];
    u16* V0 = att[slot][2];
    u16* V1 = att[slot][3];
    const int kb = srow * 36 + ssub;
    // K chunk even (k-elems [sch*8, +8)) -> K_lh0 slot ssub; odd -> K_lh1
    *(s4v*)(K0 + kb) = lo4(kr0);
    *(s4v*)(K0 + kb + 4) = hi4(kr0);
    *(s4v*)(K1 + kb) = lo4(kr1);
    *(s4v*)(K1 + kb + 4) = hi4(kr1);
    // V global chunk ch covers j [ch*8,+8): lo 4 j -> V_lh0[ch*4], hi -> V_lh1
    const int vb0 = srow * 36 + sch * 4;
    *(s4v*)(V0 + vb0) = lo4(vr0);
    *(s4v*)(V1 + vb0) = hi4(vr0);
    *(s4v*)(V0 + vb0 + 4) = lo4(vr1);
    *(s4v*)(V1 + vb0 + 4) = hi4(vr1);
  };

  const int qmin = qb * 128;

  auto compute = [&](int slot, int jt) {
    const int j0 = jt * 64;
    const u16* Kb = att[slot][lh];
    const u16* Vb0 = att[slot][2];
    const u16* Vb1 = att[slot][3];
    const u16* Vme = (lh == 0) ? Vb0 : Vb1;

    const bool special = ((j0 <= qmin + 130) && (j0 + 65 >= qmin)) || (j0 + 64 > NBLK);
    s4v ef[8];
#pragma unroll
    for (int jb = 0; jb < 2; ++jb) {
      f16v sacc;
#pragma unroll
      for (int i = 0; i < 16; ++i) sacc[i] = 0.f;
      __builtin_amdgcn_s_setprio(1);
#pragma unroll
      for (int ss = 0; ss < 4; ++ss) {
        const u16* kp = Kb + (jb * 32 + lq) * 36 + ss * 8;
        s4v a = *(const s4v*)kp;
        s4v b2 = *(const s4v*)(kp + 4);
        s8v kf = __builtin_shufflevector(a, b2, 0, 1, 2, 3, 4, 5, 6, 7);
        sacc = mfma3216(kf, qf[ss], sacc);
      }
      __builtin_amdgcn_s_setprio(0);

      if (special) {
        float e[16];
#pragma unroll
        for (int r = 0; r < 16; ++r) {
          int j = j0 + jb * 32 + (r & 3) + 8 * (r >> 2) + 4 * lh;
          float ev = fexp2(sacc[r]);
          int dd = j - qg;
          float fac = (j < NBLK) ? (((dd <= 2) && (dd >= -2)) ? 2.f : 1.f) : 0.f;
          e[r] = ev * fac;
        }
#pragma unroll
        for (int k4 = 0; k4 < 4; ++k4) {
          u32x2 w2;
          w2[0] = cvtpk(e[k4 * 4 + 0], e[k4 * 4 + 1]);
          w2[1] = cvtpk(e[k4 * 4 + 2], e[k4 * 4 + 3]);
          ef[jb * 4 + k4] = __builtin_bit_cast(s4v, w2);
        }
      } else {
#pragma unroll
        for (int k4 = 0; k4 < 4; ++k4) {
          u32x2 w2;
          w2[0] = cvtpk(fexp2(sacc[k4 * 4 + 0]), fexp2(sacc[k4 * 4 + 1]));
          w2[1] = cvtpk(fexp2(sacc[k4 * 4 + 2]), fexp2(sacc[k4 * 4 + 3]));
          ef[jb * 4 + k4] = __builtin_bit_cast(s4v, w2);
        }
      }
    }

    __builtin_amdgcn_s_setprio(1);
#pragma unroll
    for (int ks = 0; ks < 8; ++ks)
      den_acc = mfma3208(ef[ks], onesf, den_acc);
#pragma unroll
    for (int ks = 0; ks < 8; ++ks) {
      s4v vf0 = *(const s4v*)(Vme + lq * 36 + ks * 4);
      s4v vf1 = *(const s4v*)(Vme + (32 + lq) * 36 + ks * 4);
      oacc0 = mfma3208(ef[ks], vf0, oacc0);
      oacc1 = mfma3208(ef[ks], vf1, oacc1);
    }
    __builtin_amdgcn_s_setprio(0);
  };

#define LGKM_BAR                                            \
  asm volatile("s_waitcnt lgkmcnt(0)" ::: "memory");        \
  __builtin_amdgcn_s_barrier();                             \
  asm volatile("" ::: "memory");

  load_regs(0);
  stage_write(0);        // compiler inserts vmcnt wait before ds_writes
  load_regs(1);
  LGKM_BAR

#pragma unroll 1
  for (int t = 0; t < 21; ++t) {
    compute(t & 1, t);
    stage_write((t + 1) & 1);     // regs hold tile t+1 (vmcnt auto)
    if (t < 20) load_regs(t + 2); // flies across barrier, lands in iter t+1
    LGKM_BAR
  }
  compute(1, 21);

#undef LGKM_BAR

  // epilogue: oacc rows q = crow(r,lh), cols d = lq (+32); den aligned.
  const int hbase = h * 64;
#pragma unroll
  for (int r = 0; r < 16; ++r) {
    int q = qb * 128 + w * 32 + (r & 3) + 8 * (r >> 2) + 4 * lh;
    float dden = den_acc[r];
    dden += (q == 0 || q == NBLK - 1) ? 2.f : ((q == 1 || q == NBLK - 2) ? 1.f : 0.f);
    float rr = 1.f / dden;
    int t = 3 * q + s;
    if (q < NBLK && t < 4096) {
      float* orow = out + ((size_t)b * 4096 + t) * 1024 + hbase + lq;
      orow[0] = oacc0[r] * rr;
      orow[32] = oacc1[r] * rr;
    }
  }
}

extern "C" void kernel_launch(void* const* d_in, const int* in_sizes, int n_in,
                              void* d_out, int out_size, void* d_ws, size_t ws_size,
                              hipStream_t stream) {
  const float* x  = (const float*)d_in[0];
  const float* Wq = (const float*)d_in[1];
  const float* Wk = (const float*)d_in[2];
  const float* Wv = (const float*)d_in[3];
  float* out = (float*)d_out;

  u16* ws = (u16*)d_ws;
  u16* xb = ws;                        // 8320*1024            = 8,519,680 elems
  u16* Wt = xb + 8519680;              // 3*1024*1024          = 3,145,728
  u16* Qp = Wt + 3145728;              // 96*1366*64           = 8,392,704
  u16* Kp = Qp + 8392704;              // 8,392,704
  u16* Vt = Kp + 8392704;              // 96*64*1376           = 8,454,144 (+256 guard)

  k_prep<<<dim3(7257), 256, 0, stream>>>(x, Wq, Wk, Wv, xb, Wt, Vt);
  k_gemm_qkv<<<dim3(65, 8, 3), 256, 0, stream>>>(xb, Wt, Qp, Kp, Vt);
  k_attn<<<dim3(1056), 256, 0, stream>>>(Qp, Kp, Vt, out);
}

// Round 11
// 207.939 us; speedup vs baseline: 1.0808x; 1.0466x over previous
//
#include <hip/hip_runtime.h>
#include <hip/hip_bf16.h>

typedef unsigned int u32;
typedef unsigned short u16;
typedef short s8v __attribute__((ext_vector_type(8)));
typedef short s4v __attribute__((ext_vector_type(4)));
typedef float f4v __attribute__((ext_vector_type(4)));
typedef float f16v __attribute__((ext_vector_type(16)));
typedef u32 u32x2 __attribute__((ext_vector_type(2)));
typedef u32 u32x4 __attribute__((ext_vector_type(4)));

// Problem constants: B=2, L=4096, D=1024, HEADS=16, KEY=SPH=64, STEP=3
// new_len=4098, blocks P=1366, combos = B*3*H = 96
#define NBLK 1366
#define VROW 1376   // padded V row stride (16B aligned)
#define QSCALE 0.18033688011112042f   // 0.125 * log2(e), folded into Q

__device__ __forceinline__ u16 f2b(float f) {
  u32 u = __builtin_bit_cast(u32, f);
  u = (u + 0x7FFFu + ((u >> 16) & 1u)) >> 16;
  return (u16)u;
}

__device__ __forceinline__ u32 cvtpk(float a, float b) {
  u32 r;
  asm("v_cvt_pk_bf16_f32 %0, %1, %2" : "=v"(r) : "v"(a), "v"(b));
  return r;
}

__device__ __forceinline__ float fexp2(float x) {
#if defined(__has_builtin)
#if __has_builtin(__builtin_amdgcn_exp2f)
  return __builtin_amdgcn_exp2f(x);
#define FEXP2_DONE 1
#endif
#endif
#ifndef FEXP2_DONE
  float r;
  asm("v_exp_f32 %0, %1" : "=v"(r) : "v"(x));
  return r;
#endif
}

__device__ __forceinline__ void gll16(const void* g, void* l) {
  __builtin_amdgcn_global_load_lds(
      (const __attribute__((address_space(1))) u32*)g,
      (__attribute__((address_space(3))) u32*)l, 16, 0, 0);
}

__device__ __forceinline__ f4v mfma32(s8v a, s8v b, f4v c) {
  return __builtin_amdgcn_mfma_f32_16x16x32_bf16(a, b, c, 0, 0, 0);
}

__device__ __forceinline__ f16v mfma3216(s8v a, s8v b, f16v c) {
  return __builtin_amdgcn_mfma_f32_32x32x16_bf16(a, b, c, 0, 0, 0);
}

__device__ __forceinline__ s4v lo4(s8v v) {
  return __builtin_shufflevector(v, v, 0, 1, 2, 3);
}
__device__ __forceinline__ s4v hi4(s8v v) {
  return __builtin_shufflevector(v, v, 4, 5, 6, 7);
}

// ---- pass 1 (fused prep): blocks [0,4160): x f32 -> xb bf16 (zero pads);
// blocks [4160,7232): W transpose+convert; blocks [7232,7257): V pad-zero.
__global__ __launch_bounds__(256) void k_prep(const float* __restrict__ x,
                                              const float* __restrict__ Wq,
                                              const float* __restrict__ Wk,
                                              const float* __restrict__ Wv,
                                              u16* __restrict__ xb,
                                              u16* __restrict__ Wt,
                                              u16* __restrict__ Vt) {
  const int bid = blockIdx.x;
  const int tid = threadIdx.x;
  if (bid < 4160) {
    long base = ((long)bid * 256 + tid) * 8;
    if (base >= 8320L * 1024L) return;
    int m = (int)(base >> 10);
    int c = (int)(base & 1023);
    int b = m / 4098;
    int t = m - b * 4098;
    s8v pack;
    if (m < 8196 && t < 4096) {
      const float* src = x + ((size_t)b * 4096 + t) * 1024 + c;
      float4 v0 = *(const float4*)(src);
      float4 v1 = *(const float4*)(src + 4);
      pack[0] = (short)f2b(v0.x); pack[1] = (short)f2b(v0.y);
      pack[2] = (short)f2b(v0.z); pack[3] = (short)f2b(v0.w);
      pack[4] = (short)f2b(v1.x); pack[5] = (short)f2b(v1.y);
      pack[6] = (short)f2b(v1.z); pack[7] = (short)f2b(v1.w);
    } else {
#pragma unroll
      for (int i = 0; i < 8; ++i) pack[i] = 0;
    }
    *(s8v*)(xb + base) = pack;
  } else if (bid < 7232) {
    __shared__ float tile[32][33];
    int bid3 = bid - 4160;
    int z = bid3 >> 10;
    int rem = bid3 & 1023;
    const float* W = (z == 0) ? Wq : ((z == 1) ? Wk : Wv);
    u16* dst = Wt + (size_t)z * 1024 * 1024;
    int n0 = (rem & 31) * 32, k0 = (rem >> 5) * 32;
    int tx = tid & 31, ty = tid >> 5;
#pragma unroll
    for (int i = 0; i < 4; ++i)
      tile[ty + i * 8][tx] = W[(size_t)(k0 + ty + i * 8) * 1024 + n0 + tx];
    __syncthreads();
#pragma unroll
    for (int i = 0; i < 4; ++i)
      dst[(size_t)(n0 + ty + i * 8) * 1024 + k0 + tx] = f2b(tile[tx][ty + i * 8]);
  } else {
    // zero V pad columns p in [1366,1376) for all 6144 (combo,d) rows + guard
    int gidx = (bid - 7232) * 256 + tid;
    if (gidx < 6144) {
      u16* dst = Vt + (size_t)gidx * VROW + NBLK;
#pragma unroll
      for (int i = 0; i < 10; ++i) dst[i] = 0;
    } else if (gidx < 6400) {
      Vt[(size_t)6144 * VROW + (gidx - 6144)] = 0;
    }
  }
}

// ---- pass 2: qkv GEMM (R7 structure, unchanged -- session best): 128x128
// tile, BK=32, 2-slot LDS ring with counted vmcnt(4); V transposed through
// LDS epilogue with sequential p-runs.
__global__ __launch_bounds__(256) void k_gemm_qkv(const u16* __restrict__ xb,
                                                  const u16* __restrict__ Wt,
                                                  u16* __restrict__ Qp,
                                                  u16* __restrict__ Kp,
                                                  u16* __restrict__ Vt) {
  const int zid = blockIdx.z;
  const int m0 = blockIdx.x * 128;
  const int n0 = blockIdx.y * 128;
  const u16* Bg = Wt + (size_t)zid * 1024 * 1024 + (size_t)n0 * 1024;

  __shared__ __align__(16) u16 shl[16384];
  u16* A0 = shl;
  u16* A1 = shl + 4096;
  u16* B0 = shl + 8192;
  u16* B1 = shl + 12288;

  const int tid = threadIdx.x;
  const int lane = tid & 63;
  const int w = tid >> 6;
  const int wr = w >> 1, wc = w & 1;
  const int lo = lane & 15, g = lane >> 4;

  const int lrow = lane >> 2;
  const int csrc = (lane & 3) ^ ((lane >> 3) & 3);
  const int rsw = (g ^ ((lo >> 1) & 3)) << 4;

  f4v acc[4][4];
#pragma unroll
  for (int i = 0; i < 4; ++i)
#pragma unroll
    for (int j = 0; j < 4; ++j) {
      f4v z = {0.f, 0.f, 0.f, 0.f};
      acc[i][j] = z;
    }

  auto stage = [&](int kt, u16* Ab, u16* Bb) {
#pragma unroll
    for (int c = 0; c < 2; ++c) {
      int rloc = w * 32 + c * 16 + lrow;
      gll16(xb + (size_t)(m0 + rloc) * 1024 + kt + csrc * 8,
            Ab + (w * 32 + c * 16) * 32);
      gll16(Bg + (size_t)rloc * 1024 + kt + csrc * 8,
            Bb + (w * 32 + c * 16) * 32);
    }
  };

  auto compute = [&](const u16* Ab, const u16* Bb) {
    s8v af[4], bf[4];
#pragma unroll
    for (int i = 0; i < 4; ++i) {
      int ar = wr * 64 + i * 16 + lo;
      af[i] = *(const s8v*)((const char*)Ab + ar * 64 + rsw);
      int br = wc * 64 + i * 16 + lo;
      bf[i] = *(const s8v*)((const char*)Bb + br * 64 + rsw);
    }
    __builtin_amdgcn_s_setprio(1);
#pragma unroll
    for (int i = 0; i < 4; ++i)
#pragma unroll
      for (int j = 0; j < 4; ++j)
        acc[i][j] = mfma32(af[i], bf[j], acc[i][j]);
    __builtin_amdgcn_s_setprio(0);
  };

#define BAR_VM4                                             \
  asm volatile("s_waitcnt vmcnt(4)" ::: "memory");          \
  __builtin_amdgcn_s_barrier();                             \
  asm volatile("" ::: "memory");
#define BAR_LGKM                                            \
  asm volatile("s_waitcnt lgkmcnt(0)" ::: "memory");        \
  __builtin_amdgcn_s_barrier();                             \
  asm volatile("" ::: "memory");

  stage(0, A0, B0);
#pragma unroll 1
  for (int kk = 0; kk < 15; ++kk) {
    int kt = kk * 64;
    stage(kt + 32, A1, B1);
    BAR_VM4
    compute(A0, B0);
    BAR_LGKM
    stage(kt + 64, A0, B0);
    BAR_VM4
    compute(A1, B1);
    BAR_LGKM
  }
  stage(31 * 32, A1, B1);
  BAR_VM4
  compute(A0, B0);
  BAR_LGKM
  asm volatile("s_waitcnt vmcnt(0)" ::: "memory");
  __builtin_amdgcn_s_barrier();
  asm volatile("" ::: "memory");
  compute(A1, B1);
  __syncthreads();

#undef BAR_VM4
#undef BAR_LGKM

  const float esc = (zid == 0) ? QSCALE : 1.0f;
  if (zid != 2) {
    u16* dq = (zid == 0) ? Qp : Kp;
#pragma unroll
    for (int i = 0; i < 4; ++i) {
#pragma unroll
      for (int r = 0; r < 4; ++r) {
        int m = m0 + wr * 64 + i * 16 + g * 4 + r;
        if (m >= 8196) continue;
        int b = m / 4098;
        int t = m - b * 4098;
        int s = t % 3;
        int p = t / 3;
        int cb = (b * 3 + s) * 16;
#pragma unroll
        for (int j = 0; j < 4; ++j) {
          int n = n0 + wc * 64 + j * 16 + lo;
          int h = n >> 6, d = n & 63;
          dq[(size_t)((cb + h) * NBLK + p) * 64 + d] = f2b(acc[i][j][r] * esc);
        }
      }
    }
  } else {
    u16* tile = shl;
#pragma unroll
    for (int i = 0; i < 4; ++i)
#pragma unroll
      for (int r = 0; r < 4; ++r) {
        int ml = wr * 64 + i * 16 + g * 4 + r;
#pragma unroll
        for (int j = 0; j < 4; ++j) {
          int nl = wc * 64 + j * 16 + lo;
          tile[ml * 128 + nl] = f2b(acc[i][j][r]);
        }
      }
    __syncthreads();
    for (int pair = tid; pair < 384; pair += 256) {
      int nl = pair & 127;
      int s = pair >> 7;
      int n = n0 + nl;
      int h = n >> 6, d = n & 63;
      for (int b = 0; b < 2; ++b) {
        int mlo = m0 > b * 4098 ? m0 : b * 4098;
        int cap = b * 4098 + 4096;
        int mhi = (m0 + 128 < cap) ? m0 + 128 : cap;
        if (mlo >= mhi) continue;
        int t_lo = mlo - b * 4098;
        int add = (s - (t_lo % 3) + 3) % 3;
        int t = t_lo + add;
        int tend = mhi - b * 4098;
        u16* dst = Vt + (size_t)(((b * 3 + s) * 16 + h) * 64 + d) * VROW;
        for (; t < tend; t += 3)
          dst[t / 3] = tile[(b * 4098 + t - m0) * 128 + nl];
      }
    }
  }
}

// ---- pass 3: attention v4 -- v3 structure (72B-pad half-buffers, reg-staged
// double buffer, 1 barrier/tile) with two MFMA-side cuts:
//  (a) PV paired to K=16: permlane32_swap builds the 8-bf16 A-frag from own+
//      partner cvtpk pairs (dst.hi<->src.lo semantics); 16 mfma3208 -> 8
//      mfma3216 per tile.
//  (b) den on VALU: scalar f32 partials per lane (q = lq is lane-local in the
//      swapped layout), shfl_xor(32) + 16 end shuffles to crow rows.
__global__ __launch_bounds__(256, 4) void k_attn(const u16* __restrict__ Qp,
                                                 const u16* __restrict__ Kp,
                                                 const u16* __restrict__ Vt,
                                                 float* __restrict__ out) {
  const int wg = blockIdx.x;                 // 1056 = 8*132
  const int idx = (wg & 7) * 132 + (wg >> 3);
  const int combo = idx / 11;
  const int qb = idx - combo * 11;           // q-block [0,11), 128 q each
  const int b = combo / 48;
  const int rem = combo - b * 48;
  const int s = rem >> 4;
  const int h = rem & 15;
  const int tid = threadIdx.x, lane = tid & 63, w = tid >> 6;
  const int lq = lane & 31, lh = lane >> 5;

  const u16* Qg = Qp + (size_t)combo * (NBLK * 64);
  const u16* Kg = Kp + (size_t)combo * (NBLK * 64);
  const u16* Vg = Vt + (size_t)combo * (64 * VROW);

  // [slot][buf: K_lh0, K_lh1, V_lh0, V_lh1][64 rows * 36 u16 (72B: 64B+8B pad)]
  __shared__ __align__(16) u16 att[2][4][64 * 36];

  const int qg = qb * 128 + w * 32 + lq;     // this lane's q
  const int qc = (qg < NBLK) ? qg : (NBLK - 1);
  s8v qf[4];
#pragma unroll
  for (int ss = 0; ss < 4; ++ss)
    qf[ss] = *(const s8v*)(Qg + (size_t)qc * 64 + ss * 16 + lh * 8);

  f16v oacc0, oacc1;
#pragma unroll
  for (int i = 0; i < 16; ++i) { oacc0[i] = 0.f; oacc1[i] = 0.f; }
  float dpart[4] = {0.f, 0.f, 0.f, 0.f};

  // staging: thread owns global 16B chunks c0=2*tid, c0+1 of both K and V
  // tiles (row = c0>>3 in [0,64), ch = c0&7 even).
  const int srow = tid >> 2;                 // (2*tid)>>3
  const int sch = (tid & 3) * 2;             // even chunk
  const int ssub = (tid & 3) * 8;            // (ch>>1)*8 u16 within half-row
  s8v kr0, kr1, vr0, vr1;

  auto load_regs = [&](int jt) {
    const int j0 = jt * 64;
    const u16* kp = Kg + (size_t)(j0 + srow) * 64 + sch * 8;
    kr0 = *(const s8v*)(kp);
    kr1 = *(const s8v*)(kp + 8);
    const u16* vp = Vg + (size_t)srow * VROW + j0 + sch * 8;
    vr0 = *(const s8v*)(vp);
    vr1 = *(const s8v*)(vp + 8);
  };

  auto stage_write = [&](int slot) {
    u16* K0 = att[slot][0];
    u16* K1 = att[slot][1];
    u16* V0 = att[slot][2];
    u16* V1 = att[slot][3];
    const int kb = srow * 36 + ssub;
    *(s4v*)(K0 + kb) = lo4(kr0);
    *(s4v*)(K0 + kb + 4) = hi4(kr0);
    *(s4v*)(K1 + kb) = lo4(kr1);
    *(s4v*)(K1 + kb + 4) = hi4(kr1);
    const int vb0 = srow * 36 + sch * 4;
    *(s4v*)(V0 + vb0) = lo4(vr0);
    *(s4v*)(V1 + vb0) = hi4(vr0);
    *(s4v*)(V0 + vb0 + 4) = lo4(vr1);
    *(s4v*)(V1 + vb0 + 4) = hi4(vr1);
  };

  const int qmin = qb * 128;

  auto compute = [&](int slot, int jt) {
    const int j0 = jt * 64;
    const u16* Kb = att[slot][lh];
    const u16* Vl0 = att[slot][2];
    const u16* Vl1 = att[slot][3];

    const bool special = ((j0 <= qmin + 130) && (j0 + 65 >= qmin)) || (j0 + 64 > NBLK);
#pragma unroll
    for (int jb = 0; jb < 2; ++jb) {
      f16v sacc;
#pragma unroll
      for (int i = 0; i < 16; ++i) sacc[i] = 0.f;
      __builtin_amdgcn_s_setprio(1);
#pragma unroll
      for (int ss = 0; ss < 4; ++ss) {
        const u16* kp = Kb + (jb * 32 + lq) * 36 + ss * 8;
        s4v a = *(const s4v*)kp;
        s4v b2 = *(const s4v*)(kp + 4);
        s8v kf = __builtin_shufflevector(a, b2, 0, 1, 2, 3, 4, 5, 6, 7);
        sacc = mfma3216(kf, qf[ss], sacc);
      }
      __builtin_amdgcn_s_setprio(0);

      float e[16];
      if (special) {
#pragma unroll
        for (int r = 0; r < 16; ++r) {
          int j = j0 + jb * 32 + (r & 3) + 8 * (r >> 2) + 4 * lh;
          float ev = fexp2(sacc[r]);
          int dd = j - qg;
          float fac = (j < NBLK) ? (((dd <= 2) && (dd >= -2)) ? 2.f : 1.f) : 0.f;
          e[r] = ev * fac;
        }
      } else {
#pragma unroll
        for (int r = 0; r < 16; ++r) e[r] = fexp2(sacc[r]);
      }
#pragma unroll
      for (int r = 0; r < 16; ++r) dpart[r & 3] += e[r];

      // paired-K PV: per 16-j group, build 8-bf16 A-frag via 2 permlane swaps
#pragma unroll
      for (int g2 = 0; g2 < 2; ++g2) {
        u32 pe0 = cvtpk(e[g2 * 8 + 0], e[g2 * 8 + 1]);
        u32 pe1 = cvtpk(e[g2 * 8 + 2], e[g2 * 8 + 3]);
        u32 pe2 = cvtpk(e[g2 * 8 + 4], e[g2 * 8 + 5]);
        u32 pe3 = cvtpk(e[g2 * 8 + 6], e[g2 * 8 + 7]);
        asm("v_permlane32_swap_b32 %0, %1" : "+v"(pe0), "+v"(pe2));
        asm("v_permlane32_swap_b32 %0, %1" : "+v"(pe1), "+v"(pe3));
        u32x4 fw;
        fw[0] = pe0; fw[1] = pe1; fw[2] = pe2; fw[3] = pe3;
        s8v ef8 = __builtin_bit_cast(s8v, fw);
        const int ci = (jb * 4 + g2 * 2 + lh) * 4;
        s4v v0a = *(const s4v*)(Vl0 + lq * 36 + ci);
        s4v v0b = *(const s4v*)(Vl1 + lq * 36 + ci);
        s8v vf0 = __builtin_shufflevector(v0a, v0b, 0, 1, 2, 3, 4, 5, 6, 7);
        s4v v1a = *(const s4v*)(Vl0 + (32 + lq) * 36 + ci);
        s4v v1b = *(const s4v*)(Vl1 + (32 + lq) * 36 + ci);
        s8v vf1 = __builtin_shufflevector(v1a, v1b, 0, 1, 2, 3, 4, 5, 6, 7);
        __builtin_amdgcn_s_setprio(1);
        oacc0 = mfma3216(ef8, vf0, oacc0);
        oacc1 = mfma3216(ef8, vf1, oacc1);
        __builtin_amdgcn_s_setprio(0);
      }
    }
  };

#define LGKM_BAR                                            \
  asm volatile("s_waitcnt lgkmcnt(0)" ::: "memory");        \
  __builtin_amdgcn_s_barrier();                             \
  asm volatile("" ::: "memory");

  load_regs(0);
  stage_write(0);        // compiler inserts vmcnt wait before ds_writes
  load_regs(1);
  LGKM_BAR

#pragma unroll 1
  for (int t = 0; t < 21; ++t) {
    compute(t & 1, t);
    stage_write((t + 1) & 1);     // regs hold tile t+1 (vmcnt auto)
    if (t < 20) load_regs(t + 2); // flies across barrier, lands in iter t+1
    LGKM_BAR
  }
  compute(1, 21);

#undef LGKM_BAR

  // den: lane-local sum is den for q = lq (this wave); combine lh halves,
  // then broadcast to crow-indexed epilogue rows.
  float dtot = (dpart[0] + dpart[1]) + (dpart[2] + dpart[3]);
  dtot += __shfl_xor(dtot, 32, 64);

  const int hbase = h * 64;
#pragma unroll
  for (int r = 0; r < 16; ++r) {
    int cr = (r & 3) + 8 * (r >> 2) + 4 * lh;
    int q = qb * 128 + w * 32 + cr;
    float dq = __shfl(dtot, cr, 64);
    dq += (q == 0 || q == NBLK - 1) ? 2.f : ((q == 1 || q == NBLK - 2) ? 1.f : 0.f);
    float rr = 1.f / dq;
    int t = 3 * q + s;
    if (q < NBLK && t < 4096) {
      float* orow = out + ((size_t)b * 4096 + t) * 1024 + hbase + lq;
      orow[0] = oacc0[r] * rr;
      orow[32] = oacc1[r] * rr;
    }
  }
}

extern "C" void kernel_launch(void* const* d_in, const int* in_sizes, int n_in,
                              void* d_out, int out_size, void* d_ws, size_t ws_size,
                              hipStream_t stream) {
  const float* x  = (const float*)d_in[0];
  const float* Wq = (const float*)d_in[1];
  const float* Wk = (const float*)d_in[2];
  const float* Wv = (const float*)d_in[3];
  float* out = (float*)d_out;

  u16* ws = (u16*)d_ws;
  u16* xb = ws;                        // 8320*1024            = 8,519,680 elems
  u16* Wt = xb + 8519680;              // 3*1024*1024          = 3,145,728
  u16* Qp = Wt + 3145728;              // 96*1366*64           = 8,392,704
  u16* Kp = Qp + 8392704;              // 8,392,704
  u16* Vt = Kp + 8392704;              // 96*64*1376           = 8,454,144 (+256 guard)

  k_prep<<<dim3(7257), 256, 0, stream>>>(x, Wq, Wk, Wv, xb, Wt, Vt);
  k_gemm_qkv<<<dim3(65, 8, 3), 256, 0, stream>>>(xb, Wt, Qp, Kp, Vt);
  k_attn<<<dim3(1056), 256, 0, stream>>>(Qp, Kp, Vt, out);
}

// Round 12
// 202.633 us; speedup vs baseline: 1.1091x; 1.0262x over previous
//
#include <hip/hip_runtime.h>
#include <hip/hip_bf16.h>

typedef unsigned int u32;
typedef unsigned short u16;
typedef short s8v __attribute__((ext_vector_type(8)));
typedef short s4v __attribute__((ext_vector_type(4)));
typedef float f4v __attribute__((ext_vector_type(4)));
typedef float f16v __attribute__((ext_vector_type(16)));
typedef u32 u32x2 __attribute__((ext_vector_type(2)));
typedef u32 u32x4 __attribute__((ext_vector_type(4)));

// Problem constants: B=2, L=4096, D=1024, HEADS=16, KEY=SPH=64, STEP=3
// new_len=4098, blocks P=1366, combos = B*3*H = 96
#define NBLK 1366
#define VROW 1376   // padded V row stride (16B aligned)
#define QSCALE 0.18033688011112042f   // 0.125 * log2(e), folded into Q

__device__ __forceinline__ u16 f2b(float f) {
  u32 u = __builtin_bit_cast(u32, f);
  u = (u + 0x7FFFu + ((u >> 16) & 1u)) >> 16;
  return (u16)u;
}

__device__ __forceinline__ u32 cvtpk(float a, float b) {
  u32 r;
  asm("v_cvt_pk_bf16_f32 %0, %1, %2" : "=v"(r) : "v"(a), "v"(b));
  return r;
}

__device__ __forceinline__ float fexp2(float x) {
#if defined(__has_builtin)
#if __has_builtin(__builtin_amdgcn_exp2f)
  return __builtin_amdgcn_exp2f(x);
#define FEXP2_DONE 1
#endif
#endif
#ifndef FEXP2_DONE
  float r;
  asm("v_exp_f32 %0, %1" : "=v"(r) : "v"(x));
  return r;
#endif
}

__device__ __forceinline__ void gll16(const void* g, void* l) {
  __builtin_amdgcn_global_load_lds(
      (const __attribute__((address_space(1))) u32*)g,
      (__attribute__((address_space(3))) u32*)l, 16, 0, 0);
}

__device__ __forceinline__ f4v mfma32(s8v a, s8v b, f4v c) {
  return __builtin_amdgcn_mfma_f32_16x16x32_bf16(a, b, c, 0, 0, 0);
}

__device__ __forceinline__ f16v mfma3216(s8v a, s8v b, f16v c) {
  return __builtin_amdgcn_mfma_f32_32x32x16_bf16(a, b, c, 0, 0, 0);
}

__device__ __forceinline__ s4v lo4(s8v v) {
  return __builtin_shufflevector(v, v, 0, 1, 2, 3);
}
__device__ __forceinline__ s4v hi4(s8v v) {
  return __builtin_shufflevector(v, v, 4, 5, 6, 7);
}

// ---- pass 1 (fused prep): blocks [0,4160): x f32 -> xb bf16 (zero pads);
// blocks [4160,7232): W transpose+convert; blocks [7232,7257): V pad-zero.
__global__ __launch_bounds__(256) void k_prep(const float* __restrict__ x,
                                              const float* __restrict__ Wq,
                                              const float* __restrict__ Wk,
                                              const float* __restrict__ Wv,
                                              u16* __restrict__ xb,
                                              u16* __restrict__ Wt,
                                              u16* __restrict__ Vt) {
  const int bid = blockIdx.x;
  const int tid = threadIdx.x;
  if (bid < 4160) {
    long base = ((long)bid * 256 + tid) * 8;
    if (base >= 8320L * 1024L) return;
    int m = (int)(base >> 10);
    int c = (int)(base & 1023);
    int b = m / 4098;
    int t = m - b * 4098;
    s8v pack;
    if (m < 8196 && t < 4096) {
      const float* src = x + ((size_t)b * 4096 + t) * 1024 + c;
      float4 v0 = *(const float4*)(src);
      float4 v1 = *(const float4*)(src + 4);
      pack[0] = (short)f2b(v0.x); pack[1] = (short)f2b(v0.y);
      pack[2] = (short)f2b(v0.z); pack[3] = (short)f2b(v0.w);
      pack[4] = (short)f2b(v1.x); pack[5] = (short)f2b(v1.y);
      pack[6] = (short)f2b(v1.z); pack[7] = (short)f2b(v1.w);
    } else {
#pragma unroll
      for (int i = 0; i < 8; ++i) pack[i] = 0;
    }
    *(s8v*)(xb + base) = pack;
  } else if (bid < 7232) {
    __shared__ float tile[32][33];
    int bid3 = bid - 4160;
    int z = bid3 >> 10;
    int rem = bid3 & 1023;
    const float* W = (z == 0) ? Wq : ((z == 1) ? Wk : Wv);
    u16* dst = Wt + (size_t)z * 1024 * 1024;
    int n0 = (rem & 31) * 32, k0 = (rem >> 5) * 32;
    int tx = tid & 31, ty = tid >> 5;
#pragma unroll
    for (int i = 0; i < 4; ++i)
      tile[ty + i * 8][tx] = W[(size_t)(k0 + ty + i * 8) * 1024 + n0 + tx];
    __syncthreads();
#pragma unroll
    for (int i = 0; i < 4; ++i)
      dst[(size_t)(n0 + ty + i * 8) * 1024 + k0 + tx] = f2b(tile[tx][ty + i * 8]);
  } else {
    // zero V pad columns p in [1366,1376) for all 6144 (combo,d) rows + guard
    int gidx = (bid - 7232) * 256 + tid;
    if (gidx < 6144) {
      u16* dst = Vt + (size_t)gidx * VROW + NBLK;
#pragma unroll
      for (int i = 0; i < 10; ++i) dst[i] = 0;
    } else if (gidx < 6400) {
      Vt[(size_t)6144 * VROW + (gidx - 6144)] = 0;
    }
  }
}

// ---- pass 2: qkv GEMM (R7 loop structure) with m-major XCD-chunked grid:
// the 24 blocks (8 n-panels x 3 zids) sharing one A-panel are dispatch-
// adjacent on the SAME XCD -> A fetched ~once per XCD L2 instead of 24x
// from HBM. Flat grid 1560 = 8 XCDs x 195.
__global__ __launch_bounds__(256) void k_gemm_qkv(const u16* __restrict__ xb,
                                                  const u16* __restrict__ Wt,
                                                  u16* __restrict__ Qp,
                                                  u16* __restrict__ Kp,
                                                  u16* __restrict__ Vt) {
  const int wg = blockIdx.x;
  const int wid = (wg & 7) * 195 + (wg >> 3);   // XCD-chunked linear id
  const int mt = wid / 24;                      // m-tile [0,65)
  const int nz = wid - mt * 24;                 // (z,y) panel [0,24)
  const int zid = nz >> 3;
  const int m0 = mt * 128;
  const int n0 = (nz & 7) * 128;
  const u16* Bg = Wt + (size_t)zid * 1024 * 1024 + (size_t)n0 * 1024;

  __shared__ __align__(16) u16 shl[16384];
  u16* A0 = shl;
  u16* A1 = shl + 4096;
  u16* B0 = shl + 8192;
  u16* B1 = shl + 12288;

  const int tid = threadIdx.x;
  const int lane = tid & 63;
  const int w = tid >> 6;
  const int wr = w >> 1, wc = w & 1;
  const int lo = lane & 15, g = lane >> 4;

  const int lrow = lane >> 2;
  const int csrc = (lane & 3) ^ ((lane >> 3) & 3);
  const int rsw = (g ^ ((lo >> 1) & 3)) << 4;

  f4v acc[4][4];
#pragma unroll
  for (int i = 0; i < 4; ++i)
#pragma unroll
    for (int j = 0; j < 4; ++j) {
      f4v z = {0.f, 0.f, 0.f, 0.f};
      acc[i][j] = z;
    }

  auto stage = [&](int kt, u16* Ab, u16* Bb) {
#pragma unroll
    for (int c = 0; c < 2; ++c) {
      int rloc = w * 32 + c * 16 + lrow;
      gll16(xb + (size_t)(m0 + rloc) * 1024 + kt + csrc * 8,
            Ab + (w * 32 + c * 16) * 32);
      gll16(Bg + (size_t)rloc * 1024 + kt + csrc * 8,
            Bb + (w * 32 + c * 16) * 32);
    }
  };

  auto compute = [&](const u16* Ab, const u16* Bb) {
    s8v af[4], bf[4];
#pragma unroll
    for (int i = 0; i < 4; ++i) {
      int ar = wr * 64 + i * 16 + lo;
      af[i] = *(const s8v*)((const char*)Ab + ar * 64 + rsw);
      int br = wc * 64 + i * 16 + lo;
      bf[i] = *(const s8v*)((const char*)Bb + br * 64 + rsw);
    }
    __builtin_amdgcn_s_setprio(1);
#pragma unroll
    for (int i = 0; i < 4; ++i)
#pragma unroll
      for (int j = 0; j < 4; ++j)
        acc[i][j] = mfma32(af[i], bf[j], acc[i][j]);
    __builtin_amdgcn_s_setprio(0);
  };

#define BAR_VM4                                             \
  asm volatile("s_waitcnt vmcnt(4)" ::: "memory");          \
  __builtin_amdgcn_s_barrier();                             \
  asm volatile("" ::: "memory");
#define BAR_LGKM                                            \
  asm volatile("s_waitcnt lgkmcnt(0)" ::: "memory");        \
  __builtin_amdgcn_s_barrier();                             \
  asm volatile("" ::: "memory");

  stage(0, A0, B0);
#pragma unroll 1
  for (int kk = 0; kk < 15; ++kk) {
    int kt = kk * 64;
    stage(kt + 32, A1, B1);
    BAR_VM4
    compute(A0, B0);
    BAR_LGKM
    stage(kt + 64, A0, B0);
    BAR_VM4
    compute(A1, B1);
    BAR_LGKM
  }
  stage(31 * 32, A1, B1);
  BAR_VM4
  compute(A0, B0);
  BAR_LGKM
  asm volatile("s_waitcnt vmcnt(0)" ::: "memory");
  __builtin_amdgcn_s_barrier();
  asm volatile("" ::: "memory");
  compute(A1, B1);
  __syncthreads();

#undef BAR_VM4
#undef BAR_LGKM

  const float esc = (zid == 0) ? QSCALE : 1.0f;
  if (zid != 2) {
    u16* dq = (zid == 0) ? Qp : Kp;
#pragma unroll
    for (int i = 0; i < 4; ++i) {
#pragma unroll
      for (int r = 0; r < 4; ++r) {
        int m = m0 + wr * 64 + i * 16 + g * 4 + r;
        if (m >= 8196) continue;
        int b = m / 4098;
        int t = m - b * 4098;
        int s = t % 3;
        int p = t / 3;
        int cb = (b * 3 + s) * 16;
#pragma unroll
        for (int j = 0; j < 4; ++j) {
          int n = n0 + wc * 64 + j * 16 + lo;
          int h = n >> 6, d = n & 63;
          dq[(size_t)((cb + h) * NBLK + p) * 64 + d] = f2b(acc[i][j][r] * esc);
        }
      }
    }
  } else {
    u16* tile = shl;
#pragma unroll
    for (int i = 0; i < 4; ++i)
#pragma unroll
      for (int r = 0; r < 4; ++r) {
        int ml = wr * 64 + i * 16 + g * 4 + r;
#pragma unroll
        for (int j = 0; j < 4; ++j) {
          int nl = wc * 64 + j * 16 + lo;
          tile[ml * 128 + nl] = f2b(acc[i][j][r]);
        }
      }
    __syncthreads();
    for (int pair = tid; pair < 384; pair += 256) {
      int nl = pair & 127;
      int s = pair >> 7;
      int n = n0 + nl;
      int h = n >> 6, d = n & 63;
      for (int b = 0; b < 2; ++b) {
        int mlo = m0 > b * 4098 ? m0 : b * 4098;
        int cap = b * 4098 + 4096;
        int mhi = (m0 + 128 < cap) ? m0 + 128 : cap;
        if (mlo >= mhi) continue;
        int t_lo = mlo - b * 4098;
        int add = (s - (t_lo % 3) + 3) % 3;
        int t = t_lo + add;
        int tend = mhi - b * 4098;
        u16* dst = Vt + (size_t)(((b * 3 + s) * 16 + h) * 64 + d) * VROW;
        for (; t < tend; t += 3)
          dst[t / 3] = tile[(b * 4098 + t - m0) * 128 + nl];
      }
    }
  }
}

// ---- pass 3: attention v4 (unchanged from R11): 32x32 MFMA, 72B-pad
// half-buffers, reg-staged double buffer, 1 barrier/tile, paired-K PV via
// permlane32_swap, VALU denominator.
__global__ __launch_bounds__(256, 4) void k_attn(const u16* __restrict__ Qp,
                                                 const u16* __restrict__ Kp,
                                                 const u16* __restrict__ Vt,
                                                 float* __restrict__ out) {
  const int wg = blockIdx.x;                 // 1056 = 8*132
  const int idx = (wg & 7) * 132 + (wg >> 3);
  const int combo = idx / 11;
  const int qb = idx - combo * 11;           // q-block [0,11), 128 q each
  const int b = combo / 48;
  const int rem = combo - b * 48;
  const int s = rem >> 4;
  const int h = rem & 15;
  const int tid = threadIdx.x, lane = tid & 63, w = tid >> 6;
  const int lq = lane & 31, lh = lane >> 5;

  const u16* Qg = Qp + (size_t)combo * (NBLK * 64);
  const u16* Kg = Kp + (size_t)combo * (NBLK * 64);
  const u16* Vg = Vt + (size_t)combo * (64 * VROW);

  // [slot][buf: K_lh0, K_lh1, V_lh0, V_lh1][64 rows * 36 u16 (72B: 64B+8B pad)]
  __shared__ __align__(16) u16 att[2][4][64 * 36];

  const int qg = qb * 128 + w * 32 + lq;     // this lane's q
  const int qc = (qg < NBLK) ? qg : (NBLK - 1);
  s8v qf[4];
#pragma unroll
  for (int ss = 0; ss < 4; ++ss)
    qf[ss] = *(const s8v*)(Qg + (size_t)qc * 64 + ss * 16 + lh * 8);

  f16v oacc0, oacc1;
#pragma unroll
  for (int i = 0; i < 16; ++i) { oacc0[i] = 0.f; oacc1[i] = 0.f; }
  float dpart[4] = {0.f, 0.f, 0.f, 0.f};

  // staging: thread owns global 16B chunks c0=2*tid, c0+1 of both K and V
  // tiles (row = c0>>3 in [0,64), ch = c0&7 even).
  const int srow = tid >> 2;                 // (2*tid)>>3
  const int sch = (tid & 3) * 2;             // even chunk
  const int ssub = (tid & 3) * 8;            // (ch>>1)*8 u16 within half-row
  s8v kr0, kr1, vr0, vr1;

  auto load_regs = [&](int jt) {
    const int j0 = jt * 64;
    const u16* kp = Kg + (size_t)(j0 + srow) * 64 + sch * 8;
    kr0 = *(const s8v*)(kp);
    kr1 = *(const s8v*)(kp + 8);
    const u16* vp = Vg + (size_t)srow * VROW + j0 + sch * 8;
    vr0 = *(const s8v*)(vp);
    vr1 = *(const s8v*)(vp + 8);
  };

  auto stage_write = [&](int slot) {
    u16* K0 = att[slot][0];
    u16* K1 = att[slot][1];
    u16* V0 = att[slot][2];
    u16* V1 = att[slot][3];
    const int kb = srow * 36 + ssub;
    *(s4v*)(K0 + kb) = lo4(kr0);
    *(s4v*)(K0 + kb + 4) = hi4(kr0);
    *(s4v*)(K1 + kb) = lo4(kr1);
    *(s4v*)(K1 + kb + 4) = hi4(kr1);
    const int vb0 = srow * 36 + sch * 4;
    *(s4v*)(V0 + vb0) = lo4(vr0);
    *(s4v*)(V1 + vb0) = hi4(vr0);
    *(s4v*)(V0 + vb0 + 4) = lo4(vr1);
    *(s4v*)(V1 + vb0 + 4) = hi4(vr1);
  };

  const int qmin = qb * 128;

  auto compute = [&](int slot, int jt) {
    const int j0 = jt * 64;
    const u16* Kb = att[slot][lh];
    const u16* Vl0 = att[slot][2];
    const u16* Vl1 = att[slot][3];

    const bool special = ((j0 <= qmin + 130) && (j0 + 65 >= qmin)) || (j0 + 64 > NBLK);
#pragma unroll
    for (int jb = 0; jb < 2; ++jb) {
      f16v sacc;
#pragma unroll
      for (int i = 0; i < 16; ++i) sacc[i] = 0.f;
      __builtin_amdgcn_s_setprio(1);
#pragma unroll
      for (int ss = 0; ss < 4; ++ss) {
        const u16* kp = Kb + (jb * 32 + lq) * 36 + ss * 8;
        s4v a = *(const s4v*)kp;
        s4v b2 = *(const s4v*)(kp + 4);
        s8v kf = __builtin_shufflevector(a, b2, 0, 1, 2, 3, 4, 5, 6, 7);
        sacc = mfma3216(kf, qf[ss], sacc);
      }
      __builtin_amdgcn_s_setprio(0);

      float e[16];
      if (special) {
#pragma unroll
        for (int r = 0; r < 16; ++r) {
          int j = j0 + jb * 32 + (r & 3) + 8 * (r >> 2) + 4 * lh;
          float ev = fexp2(sacc[r]);
          int dd = j - qg;
          float fac = (j < NBLK) ? (((dd <= 2) && (dd >= -2)) ? 2.f : 1.f) : 0.f;
          e[r] = ev * fac;
        }
      } else {
#pragma unroll
        for (int r = 0; r < 16; ++r) e[r] = fexp2(sacc[r]);
      }
#pragma unroll
      for (int r = 0; r < 16; ++r) dpart[r & 3] += e[r];

      // paired-K PV: per 16-j group, build 8-bf16 A-frag via 2 permlane swaps
#pragma unroll
      for (int g2 = 0; g2 < 2; ++g2) {
        u32 pe0 = cvtpk(e[g2 * 8 + 0], e[g2 * 8 + 1]);
        u32 pe1 = cvtpk(e[g2 * 8 + 2], e[g2 * 8 + 3]);
        u32 pe2 = cvtpk(e[g2 * 8 + 4], e[g2 * 8 + 5]);
        u32 pe3 = cvtpk(e[g2 * 8 + 6], e[g2 * 8 + 7]);
        asm("v_permlane32_swap_b32 %0, %1" : "+v"(pe0), "+v"(pe2));
        asm("v_permlane32_swap_b32 %0, %1" : "+v"(pe1), "+v"(pe3));
        u32x4 fw;
        fw[0] = pe0; fw[1] = pe1; fw[2] = pe2; fw[3] = pe3;
        s8v ef8 = __builtin_bit_cast(s8v, fw);
        const int ci = (jb * 4 + g2 * 2 + lh) * 4;
        s4v v0a = *(const s4v*)(Vl0 + lq * 36 + ci);
        s4v v0b = *(const s4v*)(Vl1 + lq * 36 + ci);
        s8v vf0 = __builtin_shufflevector(v0a, v0b, 0, 1, 2, 3, 4, 5, 6, 7);
        s4v v1a = *(const s4v*)(Vl0 + (32 + lq) * 36 + ci);
        s4v v1b = *(const s4v*)(Vl1 + (32 + lq) * 36 + ci);
        s8v vf1 = __builtin_shufflevector(v1a, v1b, 0, 1, 2, 3, 4, 5, 6, 7);
        __builtin_amdgcn_s_setprio(1);
        oacc0 = mfma3216(ef8, vf0, oacc0);
        oacc1 = mfma3216(ef8, vf1, oacc1);
        __builtin_amdgcn_s_setprio(0);
      }
    }
  };

#define LGKM_BAR                                            \
  asm volatile("s_waitcnt lgkmcnt(0)" ::: "memory");        \
  __builtin_amdgcn_s_barrier();                             \
  asm volatile("" ::: "memory");

  load_regs(0);
  stage_write(0);        // compiler inserts vmcnt wait before ds_writes
  load_regs(1);
  LGKM_BAR

#pragma unroll 1
  for (int t = 0; t < 21; ++t) {
    compute(t & 1, t);
    stage_write((t + 1) & 1);     // regs hold tile t+1 (vmcnt auto)
    if (t < 20) load_regs(t + 2); // flies across barrier, lands in iter t+1
    LGKM_BAR
  }
  compute(1, 21);

#undef LGKM_BAR

  // den: lane-local sum is den for q = lq (this wave); combine lh halves,
  // then broadcast to crow-indexed epilogue rows.
  float dtot = (dpart[0] + dpart[1]) + (dpart[2] + dpart[3]);
  dtot += __shfl_xor(dtot, 32, 64);

  const int hbase = h * 64;
#pragma unroll
  for (int r = 0; r < 16; ++r) {
    int cr = (r & 3) + 8 * (r >> 2) + 4 * lh;
    int q = qb * 128 + w * 32 + cr;
    float dq = __shfl(dtot, cr, 64);
    dq += (q == 0 || q == NBLK - 1) ? 2.f : ((q == 1 || q == NBLK - 2) ? 1.f : 0.f);
    float rr = 1.f / dq;
    int t = 3 * q + s;
    if (q < NBLK && t < 4096) {
      float* orow = out + ((size_t)b * 4096 + t) * 1024 + hbase + lq;
      orow[0] = oacc0[r] * rr;
      orow[32] = oacc1[r] * rr;
    }
  }
}

extern "C" void kernel_launch(void* const* d_in, const int* in_sizes, int n_in,
                              void* d_out, int out_size, void* d_ws, size_t ws_size,
                              hipStream_t stream) {
  const float* x  = (const float*)d_in[0];
  const float* Wq = (const float*)d_in[1];
  const float* Wk = (const float*)d_in[2];
  const float* Wv = (const float*)d_in[3];
  float* out = (float*)d_out;

  u16* ws = (u16*)d_ws;
  u16* xb = ws;                        // 8320*1024            = 8,519,680 elems
  u16* Wt = xb + 8519680;              // 3*1024*1024          = 3,145,728
  u16* Qp = Wt + 3145728;              // 96*1366*64           = 8,392,704
  u16* Kp = Qp + 8392704;              // 8,392,704
  u16* Vt = Kp + 8392704;              // 96*64*1376           = 8,454,144 (+256 guard)

  k_prep<<<dim3(7257), 256, 0, stream>>>(x, Wq, Wk, Wv, xb, Wt, Vt);
  k_gemm_qkv<<<dim3(1560), 256, 0, stream>>>(xb, Wt, Qp, Kp, Vt);
  k_attn<<<dim3(1056), 256, 0, stream>>>(Qp, Kp, Vt, out);
}